// Round 4
// baseline (550.190 us; speedup 1.0000x reference)
//
#include <hip/hip_runtime.h>
#include <math.h>

#define SEQ     1024
#define NBATCH  8
#define NTOK    8192        // NBATCH*SEQ
#define DMODEL  512
#define DINNER  1024
#define NHEADS  16
#define DPROJ   2192
#define DPROJP  2304        // padded to multiple of 128
#define CONVDIM 1152
#define DFFN    2048

typedef short bf16x8 __attribute__((ext_vector_type(8)));
typedef float f32x4  __attribute__((ext_vector_type(4)));

__device__ inline unsigned short f2bf(float f) {
  union { float f; unsigned int u; } v; v.f = f;
  unsigned int u = v.u;
  return (unsigned short)((u + 0x7FFFu + ((u >> 16) & 1u)) >> 16);
}
__device__ inline float bf2f(unsigned short s) {
  union { unsigned int u; float f; } v; v.u = ((unsigned int)s) << 16;
  return v.f;
}

// async global->LDS, 16B per lane; lds base must be wave-uniform (lane*16 added by HW)
#define GLDS16(g, l)                                                         \
  __builtin_amdgcn_global_load_lds(                                          \
      (const __attribute__((address_space(1))) unsigned int*)(g),            \
      (__attribute__((address_space(3))) unsigned int*)(l), 16, 0, 0)

// ---------------- bf16 conversion ----------------
__global__ __launch_bounds__(256) void cvt_bf16(const float* __restrict__ s,
                                                unsigned short* __restrict__ d, int n) {
  int i = blockIdx.x * 256 + threadIdx.x;
  if (i < n) d[i] = f2bf(s[i]);
}

__global__ __launch_bounds__(256) void cvt_bf16_pad(const float* __restrict__ s,
                                                    unsigned short* __restrict__ d,
                                                    int realrows, int cols, int padrows) {
  int i = blockIdx.x * 256 + threadIdx.x;
  if (i < padrows * cols) {
    int r = i / cols;
    d[i] = (r < realrows) ? f2bf(s[i]) : (unsigned short)0;
  }
}

// ---------------- bf16 MFMA GEMM: C[M,N] = A[M,K] @ B[N,K]^T ----------------
// global_load_lds staging (m97 pattern). MODE 0: fp32 (+bias). MODE 1: bias+gelu->bf16.
// MODE 2: bf16 store, cols >= 2176 also fp32 -> aux[row*16 + col-2176].
template <int MODE>
__global__ __launch_bounds__(256)
void gemm_bt(const unsigned short* __restrict__ A, const unsigned short* __restrict__ B,
             void* __restrict__ Cout, const float* __restrict__ bias,
             float* __restrict__ aux, int K, int Nreal) {
  __shared__ unsigned short sA[128 * 32];
  __shared__ unsigned short sB[128 * 32];
  const int tid = threadIdx.x;
  const int bx = blockIdx.x, by = blockIdx.y;
  const int lane = tid & 63;
  const int wave = tid >> 6;
  const int wm = wave >> 1, wn = wave & 1;
  const int arow = tid >> 2;
  const int acol = (tid & 3) << 3;

  const unsigned short* pA = A + (size_t)(by * 128 + arow) * K + acol;
  const unsigned short* pB = B + (size_t)(bx * 128 + arow) * K + acol;
  const size_t stride64 = (size_t)64 * K;
  char* sAw = (char*)sA + wave * 1024;     // wave-uniform LDS base
  char* sBw = (char*)sB + wave * 1024;

  f32x4 acc[4][4];
#pragma unroll
  for (int i = 0; i < 4; i++)
#pragma unroll
    for (int j = 0; j < 4; j++) { f32x4 z = {0.f, 0.f, 0.f, 0.f}; acc[i][j] = z; }

  const int lrow = lane & 15;
  const int lkq = (lane >> 4) << 3;

  for (int k0 = 0; k0 < K; k0 += 32) {
    __syncthreads();
    GLDS16(pA, sAw);
    GLDS16(pA + stride64, sAw + 4096);
    GLDS16(pB, sBw);
    GLDS16(pB + stride64, sBw + 4096);
    pA += 32; pB += 32;
    __syncthreads();
    bf16x8 af[4], bfr[4];
#pragma unroll
    for (int mi = 0; mi < 4; mi++)
      af[mi] = *(const bf16x8*)&sA[(wm * 64 + mi * 16 + lrow) * 32 + lkq];
#pragma unroll
    for (int ni = 0; ni < 4; ni++)
      bfr[ni] = *(const bf16x8*)&sB[(wn * 64 + ni * 16 + lrow) * 32 + lkq];
#pragma unroll
    for (int mi = 0; mi < 4; mi++)
#pragma unroll
      for (int ni = 0; ni < 4; ni++)
        acc[mi][ni] = __builtin_amdgcn_mfma_f32_16x16x32_bf16(af[mi], bfr[ni], acc[mi][ni], 0, 0, 0);
  }

  const int row0 = by * 128 + wm * 64;
  const int col0 = bx * 128 + wn * 64;
#pragma unroll
  for (int mi = 0; mi < 4; mi++) {
#pragma unroll
    for (int ni = 0; ni < 4; ni++) {
      const int col = col0 + ni * 16 + lrow;
      if (col < Nreal) {
        const float bval = (MODE != 2 && bias) ? bias[col] : 0.f;
#pragma unroll
        for (int r = 0; r < 4; r++) {
          const int row = row0 + mi * 16 + ((lane >> 4) << 2) + r;
          float v = acc[mi][ni][r] + bval;
          if (MODE == 1) {
            float g = 0.5f * v * (1.f + erff(v * 0.7071067811865476f));
            ((unsigned short*)Cout)[(size_t)row * Nreal + col] = f2bf(g);
          } else if (MODE == 2) {
            ((unsigned short*)Cout)[(size_t)row * Nreal + col] = f2bf(v);
            if (col >= 2176) aux[(size_t)row * 16 + (col - 2176)] = v;
          } else {
            ((float*)Cout)[(size_t)row * Nreal + col] = v;
          }
        }
      }
    }
  }
}

// ---------------- dt = softplus(zdt + dt_bias); layout [dir][(b*16+h)][t] ----------------
__global__ __launch_bounds__(256)
void dt_softplus(const float* __restrict__ zdt, const float* __restrict__ dt_bias,
                 float* __restrict__ dtf, float* __restrict__ dtb) {
  int i = blockIdx.x * 256 + threadIdx.x;     // 0 .. 262143
  int dir = i >> 17;
  int rem = i & 131071;
  int row = rem >> 10;                        // b*16+h
  int t = rem & 1023;
  int b = row >> 4, h = row & 15;
  int srow = (b << 10) + (dir ? (1023 - t) : t);
  float v = zdt[(size_t)srow * 16 + h] + dt_bias[h];
  float dt = (v > 20.f) ? v : log1pf(expf(v));
  (dir ? dtb : dtf)[(row << 10) + t] = dt;
}

// ---------------- sliding-window causal dw-conv (k=4) + silu, BOTH dirs ----------------
// Emits SSD-friendly layouts: xT[b][c][t] (x transposed), bc[b][t][128] (B|C row-major),
// bT[b][n][t] (B transposed). bwd output at t'=1026-s reuses the fwd register window.
__global__ __launch_bounds__(256)
void conv_silu_t(const unsigned short* __restrict__ zxb, const float* __restrict__ cw,
                 const float* __restrict__ cb,
                 unsigned short* __restrict__ xTf, unsigned short* __restrict__ xTb,
                 unsigned short* __restrict__ bcf, unsigned short* __restrict__ bcb,
                 unsigned short* __restrict__ bTf, unsigned short* __restrict__ bTb) {
  const int tid = threadIdx.x;
  const int c = blockIdx.x * 128 + (tid & 127);     // 0..1151
  const int b = blockIdx.y;
  const int seg = blockIdx.z * 2 + (tid >> 7);      // 0..7
  const int t0 = seg << 7;
  const float w0 = cw[c * 4 + 0], w1 = cw[c * 4 + 1], w2 = cw[c * 4 + 2], w3 = cw[c * 4 + 3];
  const float bias = cb[c];
  const unsigned short* src = zxb + (size_t)(b << 10) * DPROJ + DINNER + c;
  const int n = c - 1024;                           // >=0 for B/C channels
  unsigned short* xTfp = xTf + ((size_t)(b * 1024 + c) << 10);
  unsigned short* xTbp = xTb + ((size_t)(b * 1024 + c) << 10);
  unsigned short* bcfp = bcf + (size_t)(b << 10) * 128 + n;
  unsigned short* bcbp = bcb + (size_t)(b << 10) * 128 + n;
  unsigned short* bTfp = bTf + ((size_t)((b << 6) + n) << 10);
  unsigned short* bTbp = bTb + ((size_t)((b << 6) + n) << 10);

  float r0 = 0.f, r1 = 0.f, r2 = 0.f;
  if (t0 >= 3) {
    r0 = bf2f(src[(size_t)(t0 - 3) * DPROJ]);
    r1 = bf2f(src[(size_t)(t0 - 2) * DPROJ]);
    r2 = bf2f(src[(size_t)(t0 - 1) * DPROJ]);
  }
  for (int s = t0; s < t0 + 128; s++) {
    float x = bf2f(src[(size_t)s * DPROJ]);
    float vf = bias + w0 * r0 + w1 * r1 + w2 * r2 + w3 * x;
    unsigned short of = f2bf(vf / (1.f + expf(-vf)));
    int tp = 1026 - s;
    unsigned short ob = 0;
    if (tp <= 1023) {
      float vb = bias + w0 * x + w1 * r2 + w2 * r1 + w3 * r0;
      ob = f2bf(vb / (1.f + expf(-vb)));
    }
    if (c < 1024) {
      xTfp[s] = of;
      if (tp <= 1023) xTbp[tp] = ob;
    } else {
      bcfp[(size_t)s * 128] = of;
      if (tp <= 1023) bcbp[(size_t)tp * 128] = ob;
      if (n < 64) {
        bTfp[s] = of;
        if (tp <= 1023) bTbp[tp] = ob;
      }
    }
    r0 = r1; r1 = r2; r2 = x;
  }
  if (seg == 7) {
    // window now: r0=row1021, r1=row1022, r2=row1023 -> bwd t' = 2,1,0
    float v2 = bias + w1 * r2 + w2 * r1 + w3 * r0;
    float v1 = bias + w2 * r2 + w3 * r1;
    float v0 = bias + w3 * r2;
    unsigned short o2 = f2bf(v2 / (1.f + expf(-v2)));
    unsigned short o1 = f2bf(v1 / (1.f + expf(-v1)));
    unsigned short o0 = f2bf(v0 / (1.f + expf(-v0)));
    if (c < 1024) {
      xTbp[2] = o2; xTbp[1] = o1; xTbp[0] = o0;
    } else {
      bcbp[2 * 128] = o2; bcbp[128] = o1; bcbp[0] = o0;
      if (n < 64) { bTbp[2] = o2; bTbp[1] = o1; bTbp[0] = o0; }
    }
  }
}

// ---------------- chunked SSD: one block per (dir,b,h), 16 chunks of L=64 ----------------
__global__ __launch_bounds__(256)
void ssd_chunk(const unsigned short* __restrict__ xTf, const unsigned short* __restrict__ xTb,
               const unsigned short* __restrict__ bcf, const unsigned short* __restrict__ bcb,
               const unsigned short* __restrict__ bTf, const unsigned short* __restrict__ bTb,
               const float* __restrict__ dtf, const float* __restrict__ dtb,
               const float* __restrict__ A_log, const float* __restrict__ Dp,
               unsigned short* __restrict__ yf, unsigned short* __restrict__ yb) {
  const int blk = blockIdx.x;
  const int dir = blk >> 7;
  const int b = (blk >> 4) & 7;
  const int h = blk & 15;
  const unsigned short* xT = (dir ? xTb : xTf) + ((size_t)(b * 1024 + h * 64) << 10);
  const unsigned short* bc = (dir ? bcb : bcf) + ((size_t)b << 10) * 128;
  const unsigned short* bT = (dir ? bTb : bTf) + ((size_t)(b << 6) << 10);
  const float* dts = (dir ? dtb : dtf) + ((size_t)((b << 4) + h) << 10);
  unsigned short* yo = (dir ? yb : yf);
  const float A = -expf(A_log[h]);
  const float Dh = Dp[h];
  const int tid = threadIdx.x;
  const int lane = tid & 63;
  const int w = tid >> 6;
  const int lrow = lane & 15;
  const int quad = lane >> 4;
  const int lk8 = quad << 3;
  const int bS = b << 10;

  __shared__ unsigned short Cb[64 * 72];   // [i][n]
  __shared__ unsigned short Bb[64 * 72];   // [s][n]
  __shared__ unsigned short Xt[64 * 72];   // [p][s]
  __shared__ unsigned short Bw[64 * 72];   // [n][s]  weighted
  __shared__ unsigned short Mb[64 * 72];   // [i][s]  masked
  __shared__ unsigned short Hb[64 * 72];   // [p][n]  h_init
  __shared__ float sdt_all[1024];

  {
    float4 dv = *(const float4*)(dts + tid * 4);
    *(float4*)&sdt_all[tid * 4] = dv;
  }

  f32x4 hacc[4];
#pragma unroll
  for (int j = 0; j < 4; j++) { f32x4 z = {0.f, 0.f, 0.f, 0.f}; hacc[j] = z; }

  for (int c = 0; c < 16; c++) {
    const int t0 = c << 6;
    __syncthreads();                       // LDS free (also covers sdt staging on c==0)

    // dt scan (per-wave, redundant): lane l holds dt_{t0+l}
    float dtl = sdt_all[t0 + lane];
    float v = dtl;
#pragma unroll
    for (int off = 1; off < 64; off <<= 1) {
      float o = __shfl_up(v, off);
      if (lane >= off) v += o;
    }
    const float Lv = A * v;
    const float ev = expf(Lv);
    const float LL = __shfl(Lv, 63);
    const float wv = dtl * expf(LL - Lv);
    const float dtot = expf(LL);

    // stage h_init -> LDS
#pragma unroll
    for (int j = 0; j < 4; j++)
#pragma unroll
      for (int r = 0; r < 4; r++)
        Hb[(w * 16 + quad * 4 + r) * 72 + j * 16 + lrow] = f2bf(hacc[j][r]);

    // stage Xt[p][s] (coalesced rows from xT)
#pragma unroll
    for (int pass = 0; pass < 2; pass++) {
      int u = pass * 256 + tid;
      int pl = u >> 3, tc = u & 7;
      uint4 vv = *(const uint4*)(xT + ((size_t)pl << 10) + t0 + tc * 8);
      *(uint4*)&Xt[pl * 72 + tc * 8] = vv;
    }
    // stage Bb/Cb from bc rows
#pragma unroll
    for (int pass = 0; pass < 4; pass++) {
      int u = pass * 256 + tid;
      int sl = u >> 4, c8 = u & 15;
      uint4 vv = *(const uint4*)(bc + (size_t)(t0 + sl) * 128 + c8 * 8);
      if (c8 < 8) *(uint4*)&Bb[sl * 72 + c8 * 8] = vv;
      else        *(uint4*)&Cb[sl * 72 + (c8 - 8) * 8] = vv;
    }
    // stage Bw[n][s] = bT[n][s] * wv_s (weight folded at staging)
#pragma unroll
    for (int pass = 0; pass < 2; pass++) {
      int u = pass * 256 + tid;
      int nl = u >> 3, tc = u & 7;
      uint4 raw = *(const uint4*)(bT + ((size_t)nl << 10) + t0 + tc * 8);
      const unsigned short* rp = (const unsigned short*)&raw;
      unsigned short o8[8];
#pragma unroll
      for (int k = 0; k < 8; k++) {
        float wvs = __shfl(wv, tc * 8 + k);
        o8[k] = f2bf(bf2f(rp[k]) * wvs);
      }
      *(uint4*)&Bw[nl * 72 + tc * 8] = *(const uint4*)o8;
    }
    __syncthreads();

    // GEMM1: M1[i][s] = C @ B^T
    f32x4 m1[4];
#pragma unroll
    for (int j = 0; j < 4; j++) { f32x4 z = {0.f, 0.f, 0.f, 0.f}; m1[j] = z; }
#pragma unroll
    for (int kq = 0; kq < 2; kq++) {
      bf16x8 af = *(const bf16x8*)&Cb[(w * 16 + lrow) * 72 + kq * 32 + lk8];
#pragma unroll
      for (int j = 0; j < 4; j++) {
        bf16x8 bf = *(const bf16x8*)&Bb[(j * 16 + lrow) * 72 + kq * 32 + lk8];
        m1[j] = __builtin_amdgcn_mfma_f32_16x16x32_bf16(af, bf, m1[j], 0, 0, 0);
      }
    }
    // mask + decay -> Mb
#pragma unroll
    for (int r = 0; r < 4; r++) {
      int i = w * 16 + quad * 4 + r;
      float Li = __shfl(Lv, i);
#pragma unroll
      for (int j = 0; j < 4; j++) {
        int s = j * 16 + lrow;
        float Ls = __shfl(Lv, s);
        float ds = __shfl(dtl, s);
        float val = (s <= i) ? m1[j][r] * expf(Li - Ls) * ds : 0.f;
        Mb[i * 72 + s] = f2bf(val);
      }
    }
    __syncthreads();

    // Y = M@X ; T = C@H^T ; S = Xt@Bw^T
    f32x4 Y[4], T[4], S[4];
#pragma unroll
    for (int j = 0; j < 4; j++) {
      f32x4 z = {0.f, 0.f, 0.f, 0.f};
      Y[j] = z; T[j] = z; S[j] = z;
    }
#pragma unroll
    for (int kq = 0; kq < 2; kq++) {
      bf16x8 am = *(const bf16x8*)&Mb[(w * 16 + lrow) * 72 + kq * 32 + lk8];
      bf16x8 ac = *(const bf16x8*)&Cb[(w * 16 + lrow) * 72 + kq * 32 + lk8];
      bf16x8 ax = *(const bf16x8*)&Xt[(w * 16 + lrow) * 72 + kq * 32 + lk8];
#pragma unroll
      for (int j = 0; j < 4; j++) {
        bf16x8 bx = *(const bf16x8*)&Xt[(j * 16 + lrow) * 72 + kq * 32 + lk8];
        bf16x8 bh = *(const bf16x8*)&Hb[(j * 16 + lrow) * 72 + kq * 32 + lk8];
        bf16x8 bw = *(const bf16x8*)&Bw[(j * 16 + lrow) * 72 + kq * 32 + lk8];
        Y[j] = __builtin_amdgcn_mfma_f32_16x16x32_bf16(am, bx, Y[j], 0, 0, 0);
        T[j] = __builtin_amdgcn_mfma_f32_16x16x32_bf16(ac, bh, T[j], 0, 0, 0);
        S[j] = __builtin_amdgcn_mfma_f32_16x16x32_bf16(ax, bw, S[j], 0, 0, 0);
      }
    }

    // combine + store Y (bf16), update h
#pragma unroll
    for (int r = 0; r < 4; r++) {
      int i = w * 16 + quad * 4 + r;
      float ei = __shfl(ev, i);
#pragma unroll
      for (int j = 0; j < 4; j++) {
        int p = j * 16 + lrow;
        float yv = Y[j][r] + ei * T[j][r] + Dh * bf2f(Xt[p * 72 + i]);
        yo[(size_t)(bS + t0 + i) * DINNER + h * 64 + p] = f2bf(yv);
      }
    }
#pragma unroll
    for (int j = 0; j < 4; j++)
#pragma unroll
      for (int r = 0; r < 4; r++)
        hacc[j][r] = dtot * hacc[j][r] + S[j][r];
  }
}

// ---------------- block reduction (256 threads, 4 waves) ----------------
__device__ inline float2 block_sum2_256(float a, float b) {
#pragma unroll
  for (int o = 32; o >= 1; o >>= 1) { a += __shfl_xor(a, o); b += __shfl_xor(b, o); }
  __shared__ float ra[4], rb[4];
  const int lane = threadIdx.x & 63, w = threadIdx.x >> 6;
  if (lane == 0) { ra[w] = a; rb[w] = b; }
  __syncthreads();
  float2 out;
  out.x = ra[0] + ra[1] + ra[2] + ra[3];
  out.y = rb[0] + rb[1] + rb[2] + rb[3];
  return out;
}

// ---------------- g = y*silu(z); RMS-norm; -> bf16 ----------------
__global__ __launch_bounds__(256)
void gate_rms(const unsigned short* __restrict__ yf, const unsigned short* __restrict__ yb,
              const unsigned short* __restrict__ zxb, const float* __restrict__ nw,
              unsigned short* __restrict__ gbf) {
  const int r = blockIdx.x;          // 0..16383 (dir-major)
  const int dir = r >> 13;
  const int bt = r & (NTOK - 1);
  const int b = bt >> 10, t = bt & 1023;
  const int zrow = (b << 10) + (dir ? (1023 - t) : t);
  const unsigned short* y = (dir ? yb : yf) + (size_t)bt * DINNER;
  const unsigned short* z = zxb + (size_t)zrow * DPROJ;
  const int tid = threadIdx.x;
  ushort4 yv4 = *(const ushort4*)(y + tid * 4);
  ushort4 zv4 = *(const ushort4*)(z + tid * 4);
  float y0 = bf2f(yv4.x), y1 = bf2f(yv4.y), y2 = bf2f(yv4.z), y3 = bf2f(yv4.w);
  float z0 = bf2f(zv4.x), z1 = bf2f(zv4.y), z2 = bf2f(zv4.z), z3 = bf2f(zv4.w);
  float4 g;
  g.x = y0 * (z0 / (1.f + expf(-z0)));
  g.y = y1 * (z1 / (1.f + expf(-z1)));
  g.z = y2 * (z2 / (1.f + expf(-z2)));
  g.w = y3 * (z3 / (1.f + expf(-z3)));
  float2 sr = block_sum2_256(g.x * g.x + g.y * g.y + g.z * g.z + g.w * g.w, 0.f);
  float scale = rsqrtf(sr.x * (1.f / 1024.f) + 1e-5f);
  float4 wv = *(const float4*)(nw + tid * 4);
  unsigned short* o = gbf + (size_t)r * DINNER + tid * 4;
  o[0] = f2bf(g.x * scale * wv.x);
  o[1] = f2bf(g.y * scale * wv.y);
  o[2] = f2bf(g.z * scale * wv.z);
  o[3] = f2bf(g.w * scale * wv.w);
}

// ---------------- h = fwd + 0.5*bwd + u; layernorm -> fp32 + bf16 ----------------
__global__ __launch_bounds__(256)
void combine_ln(const float* __restrict__ mo, const float* __restrict__ u,
                const float* __restrict__ w, const float* __restrict__ bias,
                float* __restrict__ hln, unsigned short* __restrict__ hbf) {
  const int bt = blockIdx.x;
  const int tid = threadIdx.x;
  const float2 mf = *(const float2*)(mo + (size_t)bt * DMODEL + tid * 2);
  const float2 mb = *(const float2*)(mo + (size_t)(NTOK + bt) * DMODEL + tid * 2);
  const float2 uu = *(const float2*)(u + (size_t)bt * DMODEL + tid * 2);
  float vx = mf.x + 0.5f * mb.x + uu.x;
  float vy = mf.y + 0.5f * mb.y + uu.y;
  float2 sr = block_sum2_256(vx + vy, vx * vx + vy * vy);
  float mean = sr.x * (1.f / 512.f);
  float var = sr.y * (1.f / 512.f) - mean * mean;
  float inv = rsqrtf(var + 1e-12f);
  float2 wv = *(const float2*)(w + tid * 2);
  float2 bv = *(const float2*)(bias + tid * 2);
  float ox = (vx - mean) * inv * wv.x + bv.x;
  float oy = (vy - mean) * inv * wv.y + bv.y;
  *(float2*)(hln + (size_t)bt * DMODEL + tid * 2) = make_float2(ox, oy);
  hbf[(size_t)bt * DMODEL + tid * 2] = f2bf(ox);
  hbf[(size_t)bt * DMODEL + tid * 2 + 1] = f2bf(oy);
}

// ---------------- out = layernorm(f2 + hln) ----------------
__global__ __launch_bounds__(256)
void final_ln(const float* __restrict__ f2, const float* __restrict__ hln,
              const float* __restrict__ w, const float* __restrict__ bias,
              float* __restrict__ outp) {
  const int bt = blockIdx.x;
  const int tid = threadIdx.x;
  const float2 a = *(const float2*)(f2 + (size_t)bt * DMODEL + tid * 2);
  const float2 h = *(const float2*)(hln + (size_t)bt * DMODEL + tid * 2);
  float vx = a.x + h.x;
  float vy = a.y + h.y;
  float2 sr = block_sum2_256(vx + vy, vx * vx + vy * vy);
  float mean = sr.x * (1.f / 512.f);
  float var = sr.y * (1.f / 512.f) - mean * mean;
  float inv = rsqrtf(var + 1e-12f);
  float2 wv = *(const float2*)(w + tid * 2);
  float2 bv = *(const float2*)(bias + tid * 2);
  *(float2*)(outp + (size_t)bt * DMODEL + tid * 2) =
      make_float2((vx - mean) * inv * wv.x + bv.x, (vy - mean) * inv * wv.y + bv.y);
}

extern "C" void kernel_launch(void* const* d_in, const int* in_sizes, int n_in,
                              void* d_out, int out_size, void* d_ws, size_t ws_size,
                              hipStream_t stream) {
  const float* item_emb   = (const float*)d_in[0];
  const float* in_proj_w  = (const float*)d_in[3];
  const float* conv_w     = (const float*)d_in[4];
  const float* conv_b     = (const float*)d_in[5];
  const float* dt_bias    = (const float*)d_in[6];
  const float* A_log      = (const float*)d_in[7];
  const float* Dp         = (const float*)d_in[8];
  const float* norm_w     = (const float*)d_in[9];
  const float* out_proj_w = (const float*)d_in[10];
  const float* ln_w       = (const float*)d_in[11];
  const float* ln_b       = (const float*)d_in[12];
  const float* w1         = (const float*)d_in[13];
  const float* b1         = (const float*)d_in[14];
  const float* w2         = (const float*)d_in[15];
  const float* b2         = (const float*)d_in[16];
  const float* fln_w      = (const float*)d_in[17];
  const float* fln_b      = (const float*)d_in[18];
  float* outp = (float*)d_out;
  char* ws = (char*)d_ws;

  // ---- workspace layout (bytes) ----
  const size_t o_ubf  = 0;                 // [8192,512]  bf16    8,388,608
  const size_t o_win  = 8388608;           // [2304,512]  bf16    2,359,296
  const size_t o_wout = 10747904;          // [512,1024]  bf16    1,048,576
  const size_t o_w1   = 11796480;          // [2048,512]  bf16    2,097,152
  const size_t o_w2   = 13893632;          // [512,2048]  bf16    2,097,152
  const size_t o_dtf  = 15990784;          // [128,1024]  f32       524,288
  const size_t o_dtb  = 16515072;
  const size_t o_zdt  = 17039360;          // [8192,16]   f32       524,288
  const size_t o_zxb  = 17563648;          // [8192,2192] bf16   35,913,728
  const size_t o_xTf  = 53477376;          // [8,1024,1024] bf16 16,777,216
  const size_t o_xTb  = 70254592;
  const size_t o_bcf  = 87031808;          // [8,1024,128]  bf16  2,097,152
  const size_t o_bcb  = 89128960;
  const size_t o_bTf  = 91226112;          // [8,64,1024]   bf16  1,048,576
  const size_t o_bTb  = 92274688;
  const size_t o_yf   = 93323264;          // [8192,1024]   bf16 16,777,216
  const size_t o_yb   = 110100480;         //                end 126,877,696
  // phase-2 aliases
  const size_t o_gbf  = o_xTf;             // [16384,1024] bf16 33.5MB (xT dead after ssd)
  const size_t o_mo   = o_zxb;             // [16384,512]  f32  (zxb dead after gate_rms)
  const size_t o_hln  = o_yf;              // [8192,512]   f32  (yf dead after gate_rms)
  const size_t o_hbf  = o_ubf;             // [8192,512]   bf16 (u_bf dead after in-proj)
  const size_t o_h1   = o_gbf;             // [8192,2048]  bf16 (gbf dead after out-proj)
  const size_t o_f2   = o_yb;              // [8192,512]   f32  (yb dead after gate_rms)

  unsigned short* u_bf  = (unsigned short*)(ws + o_ubf);
  unsigned short* winb  = (unsigned short*)(ws + o_win);
  unsigned short* woutb = (unsigned short*)(ws + o_wout);
  unsigned short* w1b   = (unsigned short*)(ws + o_w1);
  unsigned short* w2b   = (unsigned short*)(ws + o_w2);
  float* dtf = (float*)(ws + o_dtf);
  float* dtb = (float*)(ws + o_dtb);
  float* zdt = (float*)(ws + o_zdt);
  unsigned short* zxb = (unsigned short*)(ws + o_zxb);
  unsigned short* xTf = (unsigned short*)(ws + o_xTf);
  unsigned short* xTb = (unsigned short*)(ws + o_xTb);
  unsigned short* bcf = (unsigned short*)(ws + o_bcf);
  unsigned short* bcb = (unsigned short*)(ws + o_bcb);
  unsigned short* bTf = (unsigned short*)(ws + o_bTf);
  unsigned short* bTb = (unsigned short*)(ws + o_bTb);
  unsigned short* yf  = (unsigned short*)(ws + o_yf);
  unsigned short* yb  = (unsigned short*)(ws + o_yb);
  unsigned short* gbf = (unsigned short*)(ws + o_gbf);
  float* mo  = (float*)(ws + o_mo);
  float* hln = (float*)(ws + o_hln);
  unsigned short* hbf = (unsigned short*)(ws + o_hbf);
  unsigned short* h1b = (unsigned short*)(ws + o_h1);
  float* f2  = (float*)(ws + o_f2);

  // ---- bf16 conversions ----
  {
    int n = NTOK * DMODEL;
    cvt_bf16<<<(n + 255) / 256, 256, 0, stream>>>(item_emb, u_bf, n);
    cvt_bf16_pad<<<(DPROJP * DMODEL + 255) / 256, 256, 0, stream>>>(in_proj_w, winb, DPROJ, DMODEL, DPROJP);
    n = DMODEL * DINNER;
    cvt_bf16<<<(n + 255) / 256, 256, 0, stream>>>(out_proj_w, woutb, n);
    n = DFFN * DMODEL;
    cvt_bf16<<<(n + 255) / 256, 256, 0, stream>>>(w1, w1b, n);
    n = DMODEL * DFFN;
    cvt_bf16<<<(n + 255) / 256, 256, 0, stream>>>(w2, w2b, n);
  }

  // ---- in-proj: zxb[8192,2192](bf16) = u @ in_proj_w^T ; dt cols fp32 -> zdt ----
  gemm_bt<2><<<dim3(DPROJP / 128, NTOK / 128), 256, 0, stream>>>(u_bf, winb, zxb, nullptr, zdt, DMODEL, DPROJ);

  // ---- dt (softplus) to [dir][(b*16+h)][t]; conv+silu to transposed layouts ----
  dt_softplus<<<1024, 256, 0, stream>>>(zdt, dt_bias, dtf, dtb);
  conv_silu_t<<<dim3(9, NBATCH, 4), 256, 0, stream>>>(zxb, conv_w, conv_b,
                                                      xTf, xTb, bcf, bcb, bTf, bTb);

  // ---- chunked SSD: 256 blocks = (dir,b,h) ----
  ssd_chunk<<<256, 256, 0, stream>>>(xTf, xTb, bcf, bcb, bTf, bTb,
                                     dtf, dtb, A_log, Dp, yf, yb);

  // ---- gate + RMS norm -> bf16 [16384,1024] ----
  gate_rms<<<2 * NTOK, 256, 0, stream>>>(yf, yb, zxb, norm_w, gbf);

  // ---- out-proj: mo[16384,512] = g @ out_proj_w^T ----
  gemm_bt<0><<<dim3(DMODEL / 128, 2 * NTOK / 128), 256, 0, stream>>>(gbf, woutb, mo, nullptr, nullptr, DINNER, DMODEL);

  // ---- combine + first layernorm ----
  combine_ln<<<NTOK, 256, 0, stream>>>(mo, item_emb, ln_w, ln_b, hln, hbf);

  // ---- FFN ----
  gemm_bt<1><<<dim3(DFFN / 128, NTOK / 128), 256, 0, stream>>>(hbf, w1b, h1b, b1, nullptr, DMODEL, DFFN);
  gemm_bt<0><<<dim3(DMODEL / 128, NTOK / 128), 256, 0, stream>>>(h1b, w2b, f2, b2, nullptr, DFFN, DMODEL);

  // ---- final layernorm -> d_out ----
  final_ln<<<NTOK, 256, 0, stream>>>(f2, hln, fln_w, fln_b, outp);

  (void)in_sizes; (void)n_in; (void)out_size; (void)ws_size;
}

// Round 5
// 454.651 us; speedup vs baseline: 1.2101x; 1.2101x over previous
//
#include <hip/hip_runtime.h>
#include <math.h>

#define SEQ     1024
#define NBATCH  8
#define NTOK    8192        // NBATCH*SEQ
#define DMODEL  512
#define DINNER  1024
#define NHEADS  16
#define DPROJ   2192
#define DPROJP  2304        // padded to multiple of 128
#define CONVDIM 1152
#define DFFN    2048

typedef short bf16x8 __attribute__((ext_vector_type(8)));
typedef float f32x4  __attribute__((ext_vector_type(4)));

__device__ inline unsigned short f2bf(float f) {
  union { float f; unsigned int u; } v; v.f = f;
  unsigned int u = v.u;
  return (unsigned short)((u + 0x7FFFu + ((u >> 16) & 1u)) >> 16);
}
__device__ inline float bf2f(unsigned short s) {
  union { unsigned int u; float f; } v; v.u = ((unsigned int)s) << 16;
  return v.f;
}

// async global->LDS, 16B per lane; lds base must be wave-uniform (lane*16 added by HW)
#define GLDS16(g, l)                                                         \
  __builtin_amdgcn_global_load_lds(                                          \
      (const __attribute__((address_space(1))) unsigned int*)(g),            \
      (__attribute__((address_space(3))) unsigned int*)(l), 16, 0, 0)

// ---------------- bf16 conversion ----------------
__global__ __launch_bounds__(256) void cvt_bf16(const float* __restrict__ s,
                                                unsigned short* __restrict__ d, int n) {
  int i = blockIdx.x * 256 + threadIdx.x;
  if (i < n) d[i] = f2bf(s[i]);
}

__global__ __launch_bounds__(256) void cvt_bf16_pad(const float* __restrict__ s,
                                                    unsigned short* __restrict__ d,
                                                    int realrows, int cols, int padrows) {
  int i = blockIdx.x * 256 + threadIdx.x;
  if (i < padrows * cols) {
    int r = i / cols;
    d[i] = (r < realrows) ? f2bf(s[i]) : (unsigned short)0;
  }
}

// ---------------- bf16 MFMA GEMM: C[M,N] = A[M,K] @ B[N,K]^T ----------------
// global_load_lds staging (m97 pattern). MODE 0: fp32 (+bias). MODE 1: bias+gelu->bf16.
// MODE 2: bf16 store, cols >= 2176 also fp32 -> aux[row*16 + col-2176].
template <int MODE>
__global__ __launch_bounds__(256)
void gemm_bt(const unsigned short* __restrict__ A, const unsigned short* __restrict__ B,
             void* __restrict__ Cout, const float* __restrict__ bias,
             float* __restrict__ aux, int K, int Nreal) {
  __shared__ unsigned short sA[128 * 32];
  __shared__ unsigned short sB[128 * 32];
  const int tid = threadIdx.x;
  const int bx = blockIdx.x, by = blockIdx.y;
  const int lane = tid & 63;
  const int wave = tid >> 6;
  const int wm = wave >> 1, wn = wave & 1;
  const int arow = tid >> 2;
  const int acol = (tid & 3) << 3;

  const unsigned short* pA = A + (size_t)(by * 128 + arow) * K + acol;
  const unsigned short* pB = B + (size_t)(bx * 128 + arow) * K + acol;
  const size_t stride64 = (size_t)64 * K;
  char* sAw = (char*)sA + wave * 1024;     // wave-uniform LDS base
  char* sBw = (char*)sB + wave * 1024;

  f32x4 acc[4][4];
#pragma unroll
  for (int i = 0; i < 4; i++)
#pragma unroll
    for (int j = 0; j < 4; j++) { f32x4 z = {0.f, 0.f, 0.f, 0.f}; acc[i][j] = z; }

  const int lrow = lane & 15;
  const int lkq = (lane >> 4) << 3;

  for (int k0 = 0; k0 < K; k0 += 32) {
    __syncthreads();
    GLDS16(pA, sAw);
    GLDS16(pA + stride64, sAw + 4096);
    GLDS16(pB, sBw);
    GLDS16(pB + stride64, sBw + 4096);
    pA += 32; pB += 32;
    __syncthreads();
    bf16x8 af[4], bfr[4];
#pragma unroll
    for (int mi = 0; mi < 4; mi++)
      af[mi] = *(const bf16x8*)&sA[(wm * 64 + mi * 16 + lrow) * 32 + lkq];
#pragma unroll
    for (int ni = 0; ni < 4; ni++)
      bfr[ni] = *(const bf16x8*)&sB[(wn * 64 + ni * 16 + lrow) * 32 + lkq];
#pragma unroll
    for (int mi = 0; mi < 4; mi++)
#pragma unroll
      for (int ni = 0; ni < 4; ni++)
        acc[mi][ni] = __builtin_amdgcn_mfma_f32_16x16x32_bf16(af[mi], bfr[ni], acc[mi][ni], 0, 0, 0);
  }

  const int row0 = by * 128 + wm * 64;
  const int col0 = bx * 128 + wn * 64;
#pragma unroll
  for (int mi = 0; mi < 4; mi++) {
#pragma unroll
    for (int ni = 0; ni < 4; ni++) {
      const int col = col0 + ni * 16 + lrow;
      if (col < Nreal) {
        const float bval = (MODE != 2 && bias) ? bias[col] : 0.f;
#pragma unroll
        for (int r = 0; r < 4; r++) {
          const int row = row0 + mi * 16 + ((lane >> 4) << 2) + r;
          float v = acc[mi][ni][r] + bval;
          if (MODE == 1) {
            float g = 0.5f * v * (1.f + erff(v * 0.7071067811865476f));
            ((unsigned short*)Cout)[(size_t)row * Nreal + col] = f2bf(g);
          } else if (MODE == 2) {
            ((unsigned short*)Cout)[(size_t)row * Nreal + col] = f2bf(v);
            if (col >= 2176) aux[(size_t)row * 16 + (col - 2176)] = v;
          } else {
            ((float*)Cout)[(size_t)row * Nreal + col] = v;
          }
        }
      }
    }
  }
}

// ---------------- dt = softplus(zdt + dt_bias); layout [dir][(b*16+h)][t] ----------------
__global__ __launch_bounds__(256)
void dt_softplus(const float* __restrict__ zdt, const float* __restrict__ dt_bias,
                 float* __restrict__ dtf, float* __restrict__ dtb) {
  int i = blockIdx.x * 256 + threadIdx.x;     // 0 .. 262143
  int dir = i >> 17;
  int rem = i & 131071;
  int row = rem >> 10;                        // b*16+h
  int t = rem & 1023;
  int b = row >> 4, h = row & 15;
  int srow = (b << 10) + (dir ? (1023 - t) : t);
  float v = zdt[(size_t)srow * 16 + h] + dt_bias[h];
  float dt = (v > 20.f) ? v : log1pf(expf(v));
  (dir ? dtb : dtf)[(row << 10) + t] = dt;
}

// ---------------- sliding-window causal dw-conv (k=4) + silu, BOTH dirs ----------------
// Row-major bf16 outputs (coalesced per-instruction stores).
// bwd output at t'=1026-s uses rows {s..s-3} with reversed taps -> one sweep serves both.
__global__ __launch_bounds__(256)
void conv_silu_bf(const unsigned short* __restrict__ zxb, const float* __restrict__ cw,
                  const float* __restrict__ cb,
                  unsigned short* __restrict__ xcf, unsigned short* __restrict__ xcb) {
  const int tid = threadIdx.x;
  const int c = blockIdx.x * 128 + (tid & 127);     // channel 0..1151
  const int b = blockIdx.y;
  const int seg = blockIdx.z * 2 + (tid >> 7);      // 0..7 (128 steps each)
  const int t0 = seg << 7;
  const float w0 = cw[c * 4 + 0], w1 = cw[c * 4 + 1], w2 = cw[c * 4 + 2], w3 = cw[c * 4 + 3];
  const float bias = cb[c];
  const unsigned short* src = zxb + (size_t)(b << 10) * DPROJ + DINNER + c;
  unsigned short* dstf = xcf + (size_t)(b << 10) * CONVDIM + c;
  unsigned short* dstb = xcb + (size_t)(b << 10) * CONVDIM + c;
  float r0 = 0.f, r1 = 0.f, r2 = 0.f;               // rows s-3, s-2, s-1
  if (t0 >= 3) {
    r0 = bf2f(src[(size_t)(t0 - 3) * DPROJ]);
    r1 = bf2f(src[(size_t)(t0 - 2) * DPROJ]);
    r2 = bf2f(src[(size_t)(t0 - 1) * DPROJ]);
  }
  for (int s = t0; s < t0 + 128; s++) {
    float x = bf2f(src[(size_t)s * DPROJ]);
    float vf = bias + w0 * r0 + w1 * r1 + w2 * r2 + w3 * x;
    dstf[(size_t)s * CONVDIM] = f2bf(vf / (1.f + expf(-vf)));
    int tp = 1026 - s;
    if (tp <= 1023) {                               // s >= 3
      float vb = bias + w0 * x + w1 * r2 + w2 * r1 + w3 * r0;
      dstb[(size_t)tp * CONVDIM] = f2bf(vb / (1.f + expf(-vb)));
    }
    r0 = r1; r1 = r2; r2 = x;
  }
  if (seg == 7) {
    // window: r0=row1021, r1=row1022, r2=row1023; emit bwd t' = 2,1,0
    float v2 = bias + w1 * r2 + w2 * r1 + w3 * r0;
    float v1 = bias + w2 * r2 + w3 * r1;
    float v0 = bias + w3 * r2;
    dstb[(size_t)2 * CONVDIM] = f2bf(v2 / (1.f + expf(-v2)));
    dstb[(size_t)1 * CONVDIM] = f2bf(v1 / (1.f + expf(-v1)));
    dstb[0] = f2bf(v0 / (1.f + expf(-v0)));
  }
}

// ---------------- chunked SSD: one block per (dir,b,h), 16 chunks of L=64 ----------------
// Staging from row-major xc; transposes done in LDS with b128 writes (bank-benign):
//   Xt[p][s] via 2ch x 8t register repack; Bt[n][s] same, weighted by wv_s at staging.
__global__ __launch_bounds__(256)
void ssd_chunk(const unsigned short* __restrict__ xcf, const unsigned short* __restrict__ xcb,
               const float* __restrict__ dtf, const float* __restrict__ dtb,
               const float* __restrict__ A_log, const float* __restrict__ Dp,
               unsigned short* __restrict__ yf, unsigned short* __restrict__ yb) {
  const int blk = blockIdx.x;
  const int dir = blk >> 7;
  const int b = (blk >> 4) & 7;
  const int h = blk & 15;
  const unsigned short* xc = dir ? xcb : xcf;
  const float* dts = (dir ? dtb : dtf) + ((size_t)((b << 4) + h) << 10);
  unsigned short* yo = dir ? yb : yf;
  const float A = -expf(A_log[h]);
  const float Dh = Dp[h];
  const int tid = threadIdx.x;
  const int lane = tid & 63;
  const int w = tid >> 6;
  const int lrow = lane & 15;
  const int quad = lane >> 4;
  const int lk8 = quad << 3;
  const int bS = b << 10;
  const int pr = tid & 31;          // channel pair for transpose staging
  const int sg = tid >> 5;          // s-group (8 timesteps)

  __shared__ unsigned short Cb[64 * 72];   // [s][n]  raw
  __shared__ unsigned short Bb[64 * 72];   // [s][n]  raw
  __shared__ unsigned short Xt[64 * 72];   // [p][s]  transposed
  __shared__ unsigned short Bt[64 * 72];   // [n][s]  transposed, * wv_s
  __shared__ unsigned short Mb[64 * 72];   // [i][s]  masked
  __shared__ unsigned short Hb[64 * 72];   // [p][n]  h_init
  __shared__ float sdt_all[1024];

  {
    float4 dv = *(const float4*)(dts + tid * 4);
    *(float4*)&sdt_all[tid * 4] = dv;
  }

  f32x4 hacc[4];
#pragma unroll
  for (int j = 0; j < 4; j++) { f32x4 z = {0.f, 0.f, 0.f, 0.f}; hacc[j] = z; }

  for (int c = 0; c < 16; c++) {
    const int t0 = c << 6;
    __syncthreads();                 // prev chunk's LDS readers done (covers sdt on c==0)

    // dt scan (per-wave, redundant): lane l holds dt_{t0+l}
    float dtl = sdt_all[t0 + lane];
    float v = dtl;
#pragma unroll
    for (int off = 1; off < 64; off <<= 1) {
      float o = __shfl_up(v, off);
      if (lane >= off) v += o;
    }
    const float Lv = A * v;
    const float ev = expf(Lv);
    const float LL = __shfl(Lv, 63);
    const float wv = dtl * expf(LL - Lv);    // in (0, dt]: safe
    const float dtot = expf(LL);

    // stage h_init -> LDS (16 b16 scatters, ~4-way)
#pragma unroll
    for (int j = 0; j < 4; j++)
#pragma unroll
      for (int r = 0; r < 4; r++)
        Hb[(w * 16 + quad * 4 + r) * 72 + j * 16 + lrow] = f2bf(hacc[j][r]);

    // stage Bb/Cb rows (raw, coalesced uint4)
#pragma unroll
    for (int pass = 0; pass < 2; pass++) {
      int u = pass * 256 + tid;
      int sl = u >> 3, c8 = u & 7;
      const unsigned short* rowp = xc + (size_t)(bS + t0 + sl) * CONVDIM;
      uint4 vb = *(const uint4*)(rowp + 1024 + c8 * 8);
      uint4 vc = *(const uint4*)(rowp + 1088 + c8 * 8);
      *(uint4*)&Bb[sl * 72 + c8 * 8] = vb;
      *(uint4*)&Cb[sl * 72 + c8 * 8] = vc;
    }

    // stage Xt (raw) and Bt (* wv_s) via register transpose: 2 channels x 8 timesteps
    {
      unsigned int xv[8], bv[8];
      const unsigned short* base = xc + (size_t)(bS + t0 + sg * 8) * CONVDIM;
#pragma unroll
      for (int k = 0; k < 8; k++) {
        const unsigned short* rp = base + (size_t)k * CONVDIM;
        xv[k] = *(const unsigned int*)(rp + h * 64 + pr * 2);
        bv[k] = *(const unsigned int*)(rp + 1024 + pr * 2);
      }
      unsigned short x0[8], x1[8], b0[8], b1[8];
#pragma unroll
      for (int k = 0; k < 8; k++) {
        float ws = __shfl(wv, sg * 8 + k);
        x0[k] = (unsigned short)(xv[k] & 0xffff);
        x1[k] = (unsigned short)(xv[k] >> 16);
        b0[k] = f2bf(bf2f((unsigned short)(bv[k] & 0xffff)) * ws);
        b1[k] = f2bf(bf2f((unsigned short)(bv[k] >> 16)) * ws);
      }
      *(uint4*)&Xt[(pr * 2 + 0) * 72 + sg * 8] = *(const uint4*)x0;
      *(uint4*)&Xt[(pr * 2 + 1) * 72 + sg * 8] = *(const uint4*)x1;
      *(uint4*)&Bt[(pr * 2 + 0) * 72 + sg * 8] = *(const uint4*)b0;
      *(uint4*)&Bt[(pr * 2 + 1) * 72 + sg * 8] = *(const uint4*)b1;
    }
    __syncthreads();

    // GEMM1: M1[i][s] = C @ B^T (raw)
    f32x4 m1[4];
#pragma unroll
    for (int j = 0; j < 4; j++) { f32x4 z = {0.f, 0.f, 0.f, 0.f}; m1[j] = z; }
#pragma unroll
    for (int kq = 0; kq < 2; kq++) {
      bf16x8 af = *(const bf16x8*)&Cb[(w * 16 + lrow) * 72 + kq * 32 + lk8];
#pragma unroll
      for (int j = 0; j < 4; j++) {
        bf16x8 bf = *(const bf16x8*)&Bb[(j * 16 + lrow) * 72 + kq * 32 + lk8];
        m1[j] = __builtin_amdgcn_mfma_f32_16x16x32_bf16(af, bf, m1[j], 0, 0, 0);
      }
    }
    // mask + decay -> Mb
#pragma unroll
    for (int r = 0; r < 4; r++) {
      int i = w * 16 + quad * 4 + r;
      float Li = __shfl(Lv, i);
#pragma unroll
      for (int j = 0; j < 4; j++) {
        int s = j * 16 + lrow;
        float Ls = __shfl(Lv, s);
        float ds = __shfl(dtl, s);
        float val = (s <= i) ? m1[j][r] * expf(Li - Ls) * ds : 0.f;
        Mb[i * 72 + s] = f2bf(val);
      }
    }
    __syncthreads();

    // Y = M@X ; T = C@H^T ; S = Xt@Bt^T  (Bt already carries wv_s)
    f32x4 Y[4], T[4], S[4];
#pragma unroll
    for (int j = 0; j < 4; j++) {
      f32x4 z = {0.f, 0.f, 0.f, 0.f};
      Y[j] = z; T[j] = z; S[j] = z;
    }
#pragma unroll
    for (int kq = 0; kq < 2; kq++) {
      bf16x8 am = *(const bf16x8*)&Mb[(w * 16 + lrow) * 72 + kq * 32 + lk8];
      bf16x8 ac = *(const bf16x8*)&Cb[(w * 16 + lrow) * 72 + kq * 32 + lk8];
      bf16x8 ax = *(const bf16x8*)&Xt[(w * 16 + lrow) * 72 + kq * 32 + lk8];
#pragma unroll
      for (int j = 0; j < 4; j++) {
        bf16x8 bx = *(const bf16x8*)&Xt[(j * 16 + lrow) * 72 + kq * 32 + lk8];
        bf16x8 bh = *(const bf16x8*)&Hb[(j * 16 + lrow) * 72 + kq * 32 + lk8];
        bf16x8 bw = *(const bf16x8*)&Bt[(j * 16 + lrow) * 72 + kq * 32 + lk8];
        Y[j] = __builtin_amdgcn_mfma_f32_16x16x32_bf16(am, bx, Y[j], 0, 0, 0);
        T[j] = __builtin_amdgcn_mfma_f32_16x16x32_bf16(ac, bh, T[j], 0, 0, 0);
        S[j] = __builtin_amdgcn_mfma_f32_16x16x32_bf16(ax, bw, S[j], 0, 0, 0);
      }
    }

    // combine + store Y (bf16), update h
#pragma unroll
    for (int r = 0; r < 4; r++) {
      int i = w * 16 + quad * 4 + r;
      float ei = __shfl(ev, i);
#pragma unroll
      for (int j = 0; j < 4; j++) {
        int p = j * 16 + lrow;
        float yv = Y[j][r] + ei * T[j][r] + Dh * bf2f(Xt[p * 72 + i]);
        yo[(size_t)(bS + t0 + i) * DINNER + h * 64 + p] = f2bf(yv);
      }
    }
#pragma unroll
    for (int j = 0; j < 4; j++)
#pragma unroll
      for (int r = 0; r < 4; r++)
        hacc[j][r] = dtot * hacc[j][r] + S[j][r];
  }
}

// ---------------- block reduction (256 threads, 4 waves) ----------------
__device__ inline float2 block_sum2_256(float a, float b) {
#pragma unroll
  for (int o = 32; o >= 1; o >>= 1) { a += __shfl_xor(a, o); b += __shfl_xor(b, o); }
  __shared__ float ra[4], rb[4];
  const int lane = threadIdx.x & 63, w = threadIdx.x >> 6;
  if (lane == 0) { ra[w] = a; rb[w] = b; }
  __syncthreads();
  float2 out;
  out.x = ra[0] + ra[1] + ra[2] + ra[3];
  out.y = rb[0] + rb[1] + rb[2] + rb[3];
  return out;
}

// ---------------- g = y*silu(z); RMS-norm; -> bf16 ----------------
__global__ __launch_bounds__(256)
void gate_rms(const unsigned short* __restrict__ yf, const unsigned short* __restrict__ yb,
              const unsigned short* __restrict__ zxb, const float* __restrict__ nw,
              unsigned short* __restrict__ gbf) {
  const int r = blockIdx.x;          // 0..16383 (dir-major)
  const int dir = r >> 13;
  const int bt = r & (NTOK - 1);
  const int b = bt >> 10, t = bt & 1023;
  const int zrow = (b << 10) + (dir ? (1023 - t) : t);
  const unsigned short* y = (dir ? yb : yf) + (size_t)bt * DINNER;
  const unsigned short* z = zxb + (size_t)zrow * DPROJ;
  const int tid = threadIdx.x;
  ushort4 yv4 = *(const ushort4*)(y + tid * 4);
  ushort4 zv4 = *(const ushort4*)(z + tid * 4);
  float y0 = bf2f(yv4.x), y1 = bf2f(yv4.y), y2 = bf2f(yv4.z), y3 = bf2f(yv4.w);
  float z0 = bf2f(zv4.x), z1 = bf2f(zv4.y), z2 = bf2f(zv4.z), z3 = bf2f(zv4.w);
  float4 g;
  g.x = y0 * (z0 / (1.f + expf(-z0)));
  g.y = y1 * (z1 / (1.f + expf(-z1)));
  g.z = y2 * (z2 / (1.f + expf(-z2)));
  g.w = y3 * (z3 / (1.f + expf(-z3)));
  float2 sr = block_sum2_256(g.x * g.x + g.y * g.y + g.z * g.z + g.w * g.w, 0.f);
  float scale = rsqrtf(sr.x * (1.f / 1024.f) + 1e-5f);
  float4 wv = *(const float4*)(nw + tid * 4);
  unsigned short* o = gbf + (size_t)r * DINNER + tid * 4;
  o[0] = f2bf(g.x * scale * wv.x);
  o[1] = f2bf(g.y * scale * wv.y);
  o[2] = f2bf(g.z * scale * wv.z);
  o[3] = f2bf(g.w * scale * wv.w);
}

// ---------------- h = fwd + 0.5*bwd + u; layernorm -> fp32 + bf16 ----------------
__global__ __launch_bounds__(256)
void combine_ln(const float* __restrict__ mo, const float* __restrict__ u,
                const float* __restrict__ w, const float* __restrict__ bias,
                float* __restrict__ hln, unsigned short* __restrict__ hbf) {
  const int bt = blockIdx.x;
  const int tid = threadIdx.x;
  const float2 mf = *(const float2*)(mo + (size_t)bt * DMODEL + tid * 2);
  const float2 mb = *(const float2*)(mo + (size_t)(NTOK + bt) * DMODEL + tid * 2);
  const float2 uu = *(const float2*)(u + (size_t)bt * DMODEL + tid * 2);
  float vx = mf.x + 0.5f * mb.x + uu.x;
  float vy = mf.y + 0.5f * mb.y + uu.y;
  float2 sr = block_sum2_256(vx + vy, vx * vx + vy * vy);
  float mean = sr.x * (1.f / 512.f);
  float var = sr.y * (1.f / 512.f) - mean * mean;
  float inv = rsqrtf(var + 1e-12f);
  float2 wv = *(const float2*)(w + tid * 2);
  float2 bv = *(const float2*)(bias + tid * 2);
  float ox = (vx - mean) * inv * wv.x + bv.x;
  float oy = (vy - mean) * inv * wv.y + bv.y;
  *(float2*)(hln + (size_t)bt * DMODEL + tid * 2) = make_float2(ox, oy);
  hbf[(size_t)bt * DMODEL + tid * 2] = f2bf(ox);
  hbf[(size_t)bt * DMODEL + tid * 2 + 1] = f2bf(oy);
}

// ---------------- out = layernorm(f2 + hln) ----------------
__global__ __launch_bounds__(256)
void final_ln(const float* __restrict__ f2, const float* __restrict__ hln,
              const float* __restrict__ w, const float* __restrict__ bias,
              float* __restrict__ outp) {
  const int bt = blockIdx.x;
  const int tid = threadIdx.x;
  const float2 a = *(const float2*)(f2 + (size_t)bt * DMODEL + tid * 2);
  const float2 h = *(const float2*)(hln + (size_t)bt * DMODEL + tid * 2);
  float vx = a.x + h.x;
  float vy = a.y + h.y;
  float2 sr = block_sum2_256(vx + vy, vx * vx + vy * vy);
  float mean = sr.x * (1.f / 512.f);
  float var = sr.y * (1.f / 512.f) - mean * mean;
  float inv = rsqrtf(var + 1e-12f);
  float2 wv = *(const float2*)(w + tid * 2);
  float2 bv = *(const float2*)(bias + tid * 2);
  *(float2*)(outp + (size_t)bt * DMODEL + tid * 2) =
      make_float2((vx - mean) * inv * wv.x + bv.x, (vy - mean) * inv * wv.y + bv.y);
}

extern "C" void kernel_launch(void* const* d_in, const int* in_sizes, int n_in,
                              void* d_out, int out_size, void* d_ws, size_t ws_size,
                              hipStream_t stream) {
  const float* item_emb   = (const float*)d_in[0];
  const float* in_proj_w  = (const float*)d_in[3];
  const float* conv_w     = (const float*)d_in[4];
  const float* conv_b     = (const float*)d_in[5];
  const float* dt_bias    = (const float*)d_in[6];
  const float* A_log      = (const float*)d_in[7];
  const float* Dp         = (const float*)d_in[8];
  const float* norm_w     = (const float*)d_in[9];
  const float* out_proj_w = (const float*)d_in[10];
  const float* ln_w       = (const float*)d_in[11];
  const float* ln_b       = (const float*)d_in[12];
  const float* w1         = (const float*)d_in[13];
  const float* b1         = (const float*)d_in[14];
  const float* w2         = (const float*)d_in[15];
  const float* b2         = (const float*)d_in[16];
  const float* fln_w      = (const float*)d_in[17];
  const float* fln_b      = (const float*)d_in[18];
  float* outp = (float*)d_out;
  char* ws = (char*)d_ws;

  // ---- workspace layout (bytes) ----
  const size_t o_ubf  = 0;                 // [8192,512]  bf16    8,388,608
  const size_t o_win  = 8388608;           // [2304,512]  bf16    2,359,296
  const size_t o_wout = 10747904;          // [512,1024]  bf16    1,048,576
  const size_t o_w1   = 11796480;          // [2048,512]  bf16    2,097,152
  const size_t o_w2   = 13893632;          // [512,2048]  bf16    2,097,152
  const size_t o_dtf  = 15990784;          // [128,1024]  f32       524,288
  const size_t o_dtb  = 16515072;
  const size_t o_zdt  = 17039360;          // [8192,16]   f32       524,288
  const size_t o_zxb  = 17563648;          // [8192,2192] bf16   35,913,728
  const size_t o_xcf  = 53477376;          // [8192,1152] bf16   18,874,368
  const size_t o_xcb  = 72351744;
  const size_t o_yf   = 91226112;          // [8192,1024] bf16   16,777,216
  const size_t o_yb   = 108003328;         //               end 124,780,544
  // phase-2 aliases (regions dead by the time these are written)
  const size_t o_gbf  = o_xcf;             // [16384,1024] bf16 33.5MB (xcf/xcb dead)
  const size_t o_mo   = o_zxb;             // [16384,512]  f32  (zxb dead after gate_rms)
  const size_t o_hln  = o_yf;              // [8192,512]   f32  (yf dead after gate_rms)
  const size_t o_hbf  = o_ubf;             // [8192,512]   bf16 (u_bf dead after in-proj)
  const size_t o_h1   = o_gbf;             // [8192,2048]  bf16 (gbf dead after out-proj)
  const size_t o_f2   = o_yb;              // [8192,512]   f32  (yb dead after gate_rms)

  unsigned short* u_bf  = (unsigned short*)(ws + o_ubf);
  unsigned short* winb  = (unsigned short*)(ws + o_win);
  unsigned short* woutb = (unsigned short*)(ws + o_wout);
  unsigned short* w1b   = (unsigned short*)(ws + o_w1);
  unsigned short* w2b   = (unsigned short*)(ws + o_w2);
  float* dtf = (float*)(ws + o_dtf);
  float* dtb = (float*)(ws + o_dtb);
  float* zdt = (float*)(ws + o_zdt);
  unsigned short* zxb = (unsigned short*)(ws + o_zxb);
  unsigned short* xcf = (unsigned short*)(ws + o_xcf);
  unsigned short* xcb = (unsigned short*)(ws + o_xcb);
  unsigned short* yf  = (unsigned short*)(ws + o_yf);
  unsigned short* yb  = (unsigned short*)(ws + o_yb);
  unsigned short* gbf = (unsigned short*)(ws + o_gbf);
  float* mo  = (float*)(ws + o_mo);
  float* hln = (float*)(ws + o_hln);
  unsigned short* hbf = (unsigned short*)(ws + o_hbf);
  unsigned short* h1b = (unsigned short*)(ws + o_h1);
  float* f2  = (float*)(ws + o_f2);

  // ---- bf16 conversions ----
  {
    int n = NTOK * DMODEL;
    cvt_bf16<<<(n + 255) / 256, 256, 0, stream>>>(item_emb, u_bf, n);
    cvt_bf16_pad<<<(DPROJP * DMODEL + 255) / 256, 256, 0, stream>>>(in_proj_w, winb, DPROJ, DMODEL, DPROJP);
    n = DMODEL * DINNER;
    cvt_bf16<<<(n + 255) / 256, 256, 0, stream>>>(out_proj_w, woutb, n);
    n = DFFN * DMODEL;
    cvt_bf16<<<(n + 255) / 256, 256, 0, stream>>>(w1, w1b, n);
    n = DMODEL * DFFN;
    cvt_bf16<<<(n + 255) / 256, 256, 0, stream>>>(w2, w2b, n);
  }

  // ---- in-proj: zxb[8192,2192](bf16) = u @ in_proj_w^T ; dt cols fp32 -> zdt ----
  gemm_bt<2><<<dim3(DPROJP / 128, NTOK / 128), 256, 0, stream>>>(u_bf, winb, zxb, nullptr, zdt, DMODEL, DPROJ);

  // ---- dt (softplus) to [dir][(b*16+h)][t]; conv+silu both dirs, row-major bf16 ----
  dt_softplus<<<1024, 256, 0, stream>>>(zdt, dt_bias, dtf, dtb);
  conv_silu_bf<<<dim3(9, NBATCH, 4), 256, 0, stream>>>(zxb, conv_w, conv_b, xcf, xcb);

  // ---- chunked SSD: 256 blocks = (dir,b,h) ----
  ssd_chunk<<<256, 256, 0, stream>>>(xcf, xcb, dtf, dtb, A_log, Dp, yf, yb);

  // ---- gate + RMS norm -> bf16 [16384,1024] ----
  gate_rms<<<2 * NTOK, 256, 0, stream>>>(yf, yb, zxb, norm_w, gbf);

  // ---- out-proj: mo[16384,512] = g @ out_proj_w^T ----
  gemm_bt<0><<<dim3(DMODEL / 128, 2 * NTOK / 128), 256, 0, stream>>>(gbf, woutb, mo, nullptr, nullptr, DINNER, DMODEL);

  // ---- combine + first layernorm ----
  combine_ln<<<NTOK, 256, 0, stream>>>(mo, item_emb, ln_w, ln_b, hln, hbf);

  // ---- FFN ----
  gemm_bt<1><<<dim3(DFFN / 128, NTOK / 128), 256, 0, stream>>>(hbf, w1b, h1b, b1, nullptr, DMODEL, DFFN);
  gemm_bt<0><<<dim3(DMODEL / 128, NTOK / 128), 256, 0, stream>>>(h1b, w2b, f2, b2, nullptr, DFFN, DMODEL);

  // ---- final layernorm -> d_out ----
  final_ln<<<NTOK, 256, 0, stream>>>(f2, hln, fln_w, fln_b, outp);

  (void)in_sizes; (void)n_in; (void)out_size; (void)ws_size;
}

// Round 6
// 451.040 us; speedup vs baseline: 1.2198x; 1.0080x over previous
//
#include <hip/hip_runtime.h>
#include <math.h>

#define SEQ     1024
#define NBATCH  8
#define NTOK    8192        // NBATCH*SEQ
#define DMODEL  512
#define DINNER  1024
#define NHEADS  16
#define DPROJ   2192
#define DPROJP  2304        // padded to multiple of 128
#define CONVDIM 1152
#define DFFN    2048

typedef short bf16x8 __attribute__((ext_vector_type(8)));
typedef float f32x4  __attribute__((ext_vector_type(4)));

__device__ inline unsigned short f2bf(float f) {
  union { float f; unsigned int u; } v; v.f = f;
  unsigned int u = v.u;
  return (unsigned short)((u + 0x7FFFu + ((u >> 16) & 1u)) >> 16);
}
__device__ inline float bf2f(unsigned short s) {
  union { unsigned int u; float f; } v; v.u = ((unsigned int)s) << 16;
  return v.f;
}

// async global->LDS, 16B per lane; lds base must be wave-uniform (lane*16 added by HW)
#define GLDS16(g, l)                                                         \
  __builtin_amdgcn_global_load_lds(                                          \
      (const __attribute__((address_space(1))) unsigned int*)(g),            \
      (__attribute__((address_space(3))) unsigned int*)(l), 16, 0, 0)

// ---------------- bf16 conversion ----------------
__global__ __launch_bounds__(256) void cvt_bf16(const float* __restrict__ s,
                                                unsigned short* __restrict__ d, int n) {
  int i = blockIdx.x * 256 + threadIdx.x;
  if (i < n) d[i] = f2bf(s[i]);
}

__global__ __launch_bounds__(256) void cvt_bf16_pad(const float* __restrict__ s,
                                                    unsigned short* __restrict__ d,
                                                    int realrows, int cols, int padrows) {
  int i = blockIdx.x * 256 + threadIdx.x;
  if (i < padrows * cols) {
    int r = i / cols;
    d[i] = (r < realrows) ? f2bf(s[i]) : (unsigned short)0;
  }
}

// ---------------- bf16 MFMA GEMM: C[M,N] = A[M,K] @ B[N,K]^T ----------------
// Single-barrier double-buffered global_load_lds pipeline: GLDS into buf^1 issued
// before compute on buf; the vmcnt(0) drain at the barrier lands after the MFMAs.
// BM=128 fixed. BN in {128, 64}. 4 waves, wave tile 64 x BN/2.
// MODE 0: fp32 (+bias). MODE 1: bias+gelu->bf16. MODE 2: bf16, cols>=2176 also
// fp32 -> aux[row*16 + col-2176].
template <int MODE, int BN>
__global__ __launch_bounds__(256)
void gemm_bt(const unsigned short* __restrict__ A, const unsigned short* __restrict__ B,
             void* __restrict__ Cout, const float* __restrict__ bias,
             float* __restrict__ aux, int K, int Nreal) {
  constexpr int NI = BN / 32;              // frags per wave in N: 4 or 2
  __shared__ unsigned short sA[2][128 * 32];
  __shared__ unsigned short sB[2][BN * 32];
  const int tid = threadIdx.x;
  const int bx = blockIdx.x, by = blockIdx.y;
  const int lane = tid & 63;
  const int wave = tid >> 6;
  const int wm = wave >> 1, wn = wave & 1;
  const int arow = tid >> 2;               // 0..63
  const int acol = (tid & 3) << 3;

  const unsigned short* pA = A + (size_t)(by * 128 + arow) * K + acol;
  const unsigned short* pB = B + (size_t)(bx * BN + arow) * K + acol;
  const size_t stride64 = (size_t)64 * K;
  char* sAw[2] = { (char*)&sA[0][0] + wave * 1024, (char*)&sA[1][0] + wave * 1024 };
  char* sBw[2] = { (char*)&sB[0][0] + wave * 1024, (char*)&sB[1][0] + wave * 1024 };

  f32x4 acc[4][NI];
#pragma unroll
  for (int i = 0; i < 4; i++)
#pragma unroll
    for (int j = 0; j < NI; j++) { f32x4 z = {0.f, 0.f, 0.f, 0.f}; acc[i][j] = z; }

  // prologue: stage k0=0 into buf 0
  GLDS16(pA, sAw[0]);
  GLDS16(pA + stride64, sAw[0] + 4096);
  GLDS16(pB, sBw[0]);
  if (BN == 128) GLDS16(pB + stride64, sBw[0] + 4096);
  pA += 32; pB += 32;
  __syncthreads();

  const int lrow = lane & 15;
  const int lkq = (lane >> 4) << 3;
  int cur = 0;
  for (int k0 = 0; k0 < K; k0 += 32) {
    if (k0 + 32 < K) {
      const int nxt = cur ^ 1;
      GLDS16(pA, sAw[nxt]);
      GLDS16(pA + stride64, sAw[nxt] + 4096);
      GLDS16(pB, sBw[nxt]);
      if (BN == 128) GLDS16(pB + stride64, sBw[nxt] + 4096);
      pA += 32; pB += 32;
    }
    bf16x8 af[4], bfr[NI];
#pragma unroll
    for (int mi = 0; mi < 4; mi++)
      af[mi] = *(const bf16x8*)&sA[cur][(wm * 64 + mi * 16 + lrow) * 32 + lkq];
#pragma unroll
    for (int ni = 0; ni < NI; ni++)
      bfr[ni] = *(const bf16x8*)&sB[cur][(wn * (BN / 2) + ni * 16 + lrow) * 32 + lkq];
#pragma unroll
    for (int mi = 0; mi < 4; mi++)
#pragma unroll
      for (int ni = 0; ni < NI; ni++)
        acc[mi][ni] = __builtin_amdgcn_mfma_f32_16x16x32_bf16(af[mi], bfr[ni], acc[mi][ni], 0, 0, 0);
    __syncthreads();
    cur ^= 1;
  }

  const int row0 = by * 128 + wm * 64;
  const int col0 = bx * BN + wn * (BN / 2);
#pragma unroll
  for (int mi = 0; mi < 4; mi++) {
#pragma unroll
    for (int ni = 0; ni < NI; ni++) {
      const int col = col0 + ni * 16 + lrow;
      if (col < Nreal) {
        const float bval = (MODE != 2 && bias) ? bias[col] : 0.f;
#pragma unroll
        for (int r = 0; r < 4; r++) {
          const int row = row0 + mi * 16 + ((lane >> 4) << 2) + r;
          float v = acc[mi][ni][r] + bval;
          if (MODE == 1) {
            float g = 0.5f * v * (1.f + erff(v * 0.7071067811865476f));
            ((unsigned short*)Cout)[(size_t)row * Nreal + col] = f2bf(g);
          } else if (MODE == 2) {
            ((unsigned short*)Cout)[(size_t)row * Nreal + col] = f2bf(v);
            if (col >= 2176) aux[(size_t)row * 16 + (col - 2176)] = v;
          } else {
            ((float*)Cout)[(size_t)row * Nreal + col] = v;
          }
        }
      }
    }
  }
}

// ---------------- dt = softplus(zdt + dt_bias); layout [dir][(b*16+h)][t] ----------------
__global__ __launch_bounds__(256)
void dt_softplus(const float* __restrict__ zdt, const float* __restrict__ dt_bias,
                 float* __restrict__ dtf, float* __restrict__ dtb) {
  int i = blockIdx.x * 256 + threadIdx.x;     // 0 .. 262143
  int dir = i >> 17;
  int rem = i & 131071;
  int row = rem >> 10;                        // b*16+h
  int t = rem & 1023;
  int b = row >> 4, h = row & 15;
  int srow = (b << 10) + (dir ? (1023 - t) : t);
  float v = zdt[(size_t)srow * 16 + h] + dt_bias[h];
  float dt = (v > 20.f) ? v : log1pf(expf(v));
  (dir ? dtb : dtf)[(row << 10) + t] = dt;
}

// ---------------- sliding-window causal dw-conv (k=4) + silu, BOTH dirs ----------------
__global__ __launch_bounds__(256)
void conv_silu_bf(const unsigned short* __restrict__ zxb, const float* __restrict__ cw,
                  const float* __restrict__ cb,
                  unsigned short* __restrict__ xcf, unsigned short* __restrict__ xcb) {
  const int tid = threadIdx.x;
  const int c = blockIdx.x * 128 + (tid & 127);     // channel 0..1151
  const int b = blockIdx.y;
  const int seg = blockIdx.z * 2 + (tid >> 7);      // 0..7 (128 steps each)
  const int t0 = seg << 7;
  const float w0 = cw[c * 4 + 0], w1 = cw[c * 4 + 1], w2 = cw[c * 4 + 2], w3 = cw[c * 4 + 3];
  const float bias = cb[c];
  const unsigned short* src = zxb + (size_t)(b << 10) * DPROJ + DINNER + c;
  unsigned short* dstf = xcf + (size_t)(b << 10) * CONVDIM + c;
  unsigned short* dstb = xcb + (size_t)(b << 10) * CONVDIM + c;
  float r0 = 0.f, r1 = 0.f, r2 = 0.f;               // rows s-3, s-2, s-1
  if (t0 >= 3) {
    r0 = bf2f(src[(size_t)(t0 - 3) * DPROJ]);
    r1 = bf2f(src[(size_t)(t0 - 2) * DPROJ]);
    r2 = bf2f(src[(size_t)(t0 - 1) * DPROJ]);
  }
  for (int s = t0; s < t0 + 128; s++) {
    float x = bf2f(src[(size_t)s * DPROJ]);
    float vf = bias + w0 * r0 + w1 * r1 + w2 * r2 + w3 * x;
    dstf[(size_t)s * CONVDIM] = f2bf(vf / (1.f + expf(-vf)));
    int tp = 1026 - s;
    if (tp <= 1023) {                               // s >= 3
      float vb = bias + w0 * x + w1 * r2 + w2 * r1 + w3 * r0;
      dstb[(size_t)tp * CONVDIM] = f2bf(vb / (1.f + expf(-vb)));
    }
    r0 = r1; r1 = r2; r2 = x;
  }
  if (seg == 7) {
    float v2 = bias + w1 * r2 + w2 * r1 + w3 * r0;
    float v1 = bias + w2 * r2 + w3 * r1;
    float v0 = bias + w3 * r2;
    dstb[(size_t)2 * CONVDIM] = f2bf(v2 / (1.f + expf(-v2)));
    dstb[(size_t)1 * CONVDIM] = f2bf(v1 / (1.f + expf(-v1)));
    dstb[0] = f2bf(v0 / (1.f + expf(-v0)));
  }
}

// ---------------- chunked SSD: one block per (dir,b,h), 16 chunks of L=64 ----------------
__global__ __launch_bounds__(256)
void ssd_chunk(const unsigned short* __restrict__ xcf, const unsigned short* __restrict__ xcb,
               const float* __restrict__ dtf, const float* __restrict__ dtb,
               const float* __restrict__ A_log, const float* __restrict__ Dp,
               unsigned short* __restrict__ yf, unsigned short* __restrict__ yb) {
  const int blk = blockIdx.x;
  const int dir = blk >> 7;
  const int b = (blk >> 4) & 7;
  const int h = blk & 15;
  const unsigned short* xc = dir ? xcb : xcf;
  const float* dts = (dir ? dtb : dtf) + ((size_t)((b << 4) + h) << 10);
  unsigned short* yo = dir ? yb : yf;
  const float A = -expf(A_log[h]);
  const float Dh = Dp[h];
  const int tid = threadIdx.x;
  const int lane = tid & 63;
  const int w = tid >> 6;
  const int lrow = lane & 15;
  const int quad = lane >> 4;
  const int lk8 = quad << 3;
  const int bS = b << 10;
  const int pr = tid & 31;          // channel pair for transpose staging
  const int sg = tid >> 5;          // s-group (8 timesteps)

  __shared__ unsigned short Cb[64 * 72];   // [s][n]  raw
  __shared__ unsigned short Bb[64 * 72];   // [s][n]  raw
  __shared__ unsigned short Xt[64 * 72];   // [p][s]  transposed
  __shared__ unsigned short Bt[64 * 72];   // [n][s]  transposed, * wv_s
  __shared__ unsigned short Mb[64 * 72];   // [i][s]  masked
  __shared__ unsigned short Hb[64 * 72];   // [p][n]  h_init
  __shared__ float sdt_all[1024];

  {
    float4 dv = *(const float4*)(dts + tid * 4);
    *(float4*)&sdt_all[tid * 4] = dv;
  }

  f32x4 hacc[4];
#pragma unroll
  for (int j = 0; j < 4; j++) { f32x4 z = {0.f, 0.f, 0.f, 0.f}; hacc[j] = z; }

  for (int c = 0; c < 16; c++) {
    const int t0 = c << 6;
    __syncthreads();                 // prev chunk's LDS readers done (covers sdt on c==0)

    float dtl = sdt_all[t0 + lane];
    float v = dtl;
#pragma unroll
    for (int off = 1; off < 64; off <<= 1) {
      float o = __shfl_up(v, off);
      if (lane >= off) v += o;
    }
    const float Lv = A * v;
    const float ev = expf(Lv);
    const float LL = __shfl(Lv, 63);
    const float wv = dtl * expf(LL - Lv);    // in (0, dt]: safe
    const float dtot = expf(LL);

    // stage h_init -> LDS
#pragma unroll
    for (int j = 0; j < 4; j++)
#pragma unroll
      for (int r = 0; r < 4; r++)
        Hb[(w * 16 + quad * 4 + r) * 72 + j * 16 + lrow] = f2bf(hacc[j][r]);

    // stage Bb/Cb rows (raw, coalesced uint4)
#pragma unroll
    for (int pass = 0; pass < 2; pass++) {
      int u = pass * 256 + tid;
      int sl = u >> 3, c8 = u & 7;
      const unsigned short* rowp = xc + (size_t)(bS + t0 + sl) * CONVDIM;
      uint4 vb = *(const uint4*)(rowp + 1024 + c8 * 8);
      uint4 vc = *(const uint4*)(rowp + 1088 + c8 * 8);
      *(uint4*)&Bb[sl * 72 + c8 * 8] = vb;
      *(uint4*)&Cb[sl * 72 + c8 * 8] = vc;
    }

    // stage Xt (raw) and Bt (* wv_s) via register transpose: 2 channels x 8 timesteps
    {
      unsigned int xv[8], bv[8];
      const unsigned short* base = xc + (size_t)(bS + t0 + sg * 8) * CONVDIM;
#pragma unroll
      for (int k = 0; k < 8; k++) {
        const unsigned short* rp = base + (size_t)k * CONVDIM;
        xv[k] = *(const unsigned int*)(rp + h * 64 + pr * 2);
        bv[k] = *(const unsigned int*)(rp + 1024 + pr * 2);
      }
      unsigned short x0[8], x1[8], b0[8], b1[8];
#pragma unroll
      for (int k = 0; k < 8; k++) {
        float ws = __shfl(wv, sg * 8 + k);
        x0[k] = (unsigned short)(xv[k] & 0xffff);
        x1[k] = (unsigned short)(xv[k] >> 16);
        b0[k] = f2bf(bf2f((unsigned short)(bv[k] & 0xffff)) * ws);
        b1[k] = f2bf(bf2f((unsigned short)(bv[k] >> 16)) * ws);
      }
      *(uint4*)&Xt[(pr * 2 + 0) * 72 + sg * 8] = *(const uint4*)x0;
      *(uint4*)&Xt[(pr * 2 + 1) * 72 + sg * 8] = *(const uint4*)x1;
      *(uint4*)&Bt[(pr * 2 + 0) * 72 + sg * 8] = *(const uint4*)b0;
      *(uint4*)&Bt[(pr * 2 + 1) * 72 + sg * 8] = *(const uint4*)b1;
    }
    __syncthreads();

    // GEMM1: M1[i][s] = C @ B^T (raw)
    f32x4 m1[4];
#pragma unroll
    for (int j = 0; j < 4; j++) { f32x4 z = {0.f, 0.f, 0.f, 0.f}; m1[j] = z; }
#pragma unroll
    for (int kq = 0; kq < 2; kq++) {
      bf16x8 af = *(const bf16x8*)&Cb[(w * 16 + lrow) * 72 + kq * 32 + lk8];
#pragma unroll
      for (int j = 0; j < 4; j++) {
        bf16x8 bf = *(const bf16x8*)&Bb[(j * 16 + lrow) * 72 + kq * 32 + lk8];
        m1[j] = __builtin_amdgcn_mfma_f32_16x16x32_bf16(af, bf, m1[j], 0, 0, 0);
      }
    }
    // mask + decay -> Mb
#pragma unroll
    for (int r = 0; r < 4; r++) {
      int i = w * 16 + quad * 4 + r;
      float Li = __shfl(Lv, i);
#pragma unroll
      for (int j = 0; j < 4; j++) {
        int s = j * 16 + lrow;
        float Ls = __shfl(Lv, s);
        float ds = __shfl(dtl, s);
        float val = (s <= i) ? m1[j][r] * expf(Li - Ls) * ds : 0.f;
        Mb[i * 72 + s] = f2bf(val);
      }
    }
    __syncthreads();

    // Y = M@X ; T = C@H^T ; S = Xt@Bt^T  (Bt already carries wv_s)
    f32x4 Y[4], T[4], S[4];
#pragma unroll
    for (int j = 0; j < 4; j++) {
      f32x4 z = {0.f, 0.f, 0.f, 0.f};
      Y[j] = z; T[j] = z; S[j] = z;
    }
#pragma unroll
    for (int kq = 0; kq < 2; kq++) {
      bf16x8 am = *(const bf16x8*)&Mb[(w * 16 + lrow) * 72 + kq * 32 + lk8];
      bf16x8 ac = *(const bf16x8*)&Cb[(w * 16 + lrow) * 72 + kq * 32 + lk8];
      bf16x8 ax = *(const bf16x8*)&Xt[(w * 16 + lrow) * 72 + kq * 32 + lk8];
#pragma unroll
      for (int j = 0; j < 4; j++) {
        bf16x8 bx = *(const bf16x8*)&Xt[(j * 16 + lrow) * 72 + kq * 32 + lk8];
        bf16x8 bh = *(const bf16x8*)&Hb[(j * 16 + lrow) * 72 + kq * 32 + lk8];
        bf16x8 bw = *(const bf16x8*)&Bt[(j * 16 + lrow) * 72 + kq * 32 + lk8];
        Y[j] = __builtin_amdgcn_mfma_f32_16x16x32_bf16(am, bx, Y[j], 0, 0, 0);
        T[j] = __builtin_amdgcn_mfma_f32_16x16x32_bf16(ac, bh, T[j], 0, 0, 0);
        S[j] = __builtin_amdgcn_mfma_f32_16x16x32_bf16(ax, bw, S[j], 0, 0, 0);
      }
    }

    // combine + store Y (bf16), update h
#pragma unroll
    for (int r = 0; r < 4; r++) {
      int i = w * 16 + quad * 4 + r;
      float ei = __shfl(ev, i);
#pragma unroll
      for (int j = 0; j < 4; j++) {
        int p = j * 16 + lrow;
        float yv = Y[j][r] + ei * T[j][r] + Dh * bf2f(Xt[p * 72 + i]);
        yo[(size_t)(bS + t0 + i) * DINNER + h * 64 + p] = f2bf(yv);
      }
    }
#pragma unroll
    for (int j = 0; j < 4; j++)
#pragma unroll
      for (int r = 0; r < 4; r++)
        hacc[j][r] = dtot * hacc[j][r] + S[j][r];
  }
}

// ---------------- block reduction (256 threads, 4 waves) ----------------
__device__ inline float2 block_sum2_256(float a, float b) {
#pragma unroll
  for (int o = 32; o >= 1; o >>= 1) { a += __shfl_xor(a, o); b += __shfl_xor(b, o); }
  __shared__ float ra[4], rb[4];
  const int lane = threadIdx.x & 63, w = threadIdx.x >> 6;
  if (lane == 0) { ra[w] = a; rb[w] = b; }
  __syncthreads();
  float2 out;
  out.x = ra[0] + ra[1] + ra[2] + ra[3];
  out.y = rb[0] + rb[1] + rb[2] + rb[3];
  return out;
}

// ---------------- g = y*silu(z); RMS-norm; -> bf16 ----------------
__global__ __launch_bounds__(256)
void gate_rms(const unsigned short* __restrict__ yf, const unsigned short* __restrict__ yb,
              const unsigned short* __restrict__ zxb, const float* __restrict__ nw,
              unsigned short* __restrict__ gbf) {
  const int r = blockIdx.x;          // 0..16383 (dir-major)
  const int dir = r >> 13;
  const int bt = r & (NTOK - 1);
  const int b = bt >> 10, t = bt & 1023;
  const int zrow = (b << 10) + (dir ? (1023 - t) : t);
  const unsigned short* y = (dir ? yb : yf) + (size_t)bt * DINNER;
  const unsigned short* z = zxb + (size_t)zrow * DPROJ;
  const int tid = threadIdx.x;
  ushort4 yv4 = *(const ushort4*)(y + tid * 4);
  ushort4 zv4 = *(const ushort4*)(z + tid * 4);
  float y0 = bf2f(yv4.x), y1 = bf2f(yv4.y), y2 = bf2f(yv4.z), y3 = bf2f(yv4.w);
  float z0 = bf2f(zv4.x), z1 = bf2f(zv4.y), z2 = bf2f(zv4.z), z3 = bf2f(zv4.w);
  float4 g;
  g.x = y0 * (z0 / (1.f + expf(-z0)));
  g.y = y1 * (z1 / (1.f + expf(-z1)));
  g.z = y2 * (z2 / (1.f + expf(-z2)));
  g.w = y3 * (z3 / (1.f + expf(-z3)));
  float2 sr = block_sum2_256(g.x * g.x + g.y * g.y + g.z * g.z + g.w * g.w, 0.f);
  float scale = rsqrtf(sr.x * (1.f / 1024.f) + 1e-5f);
  float4 wv = *(const float4*)(nw + tid * 4);
  unsigned short* o = gbf + (size_t)r * DINNER + tid * 4;
  o[0] = f2bf(g.x * scale * wv.x);
  o[1] = f2bf(g.y * scale * wv.y);
  o[2] = f2bf(g.z * scale * wv.z);
  o[3] = f2bf(g.w * scale * wv.w);
}

// ---------------- h = fwd + 0.5*bwd + u; layernorm -> fp32 + bf16 ----------------
__global__ __launch_bounds__(256)
void combine_ln(const float* __restrict__ mo, const float* __restrict__ u,
                const float* __restrict__ w, const float* __restrict__ bias,
                float* __restrict__ hln, unsigned short* __restrict__ hbf) {
  const int bt = blockIdx.x;
  const int tid = threadIdx.x;
  const float2 mf = *(const float2*)(mo + (size_t)bt * DMODEL + tid * 2);
  const float2 mb = *(const float2*)(mo + (size_t)(NTOK + bt) * DMODEL + tid * 2);
  const float2 uu = *(const float2*)(u + (size_t)bt * DMODEL + tid * 2);
  float vx = mf.x + 0.5f * mb.x + uu.x;
  float vy = mf.y + 0.5f * mb.y + uu.y;
  float2 sr = block_sum2_256(vx + vy, vx * vx + vy * vy);
  float mean = sr.x * (1.f / 512.f);
  float var = sr.y * (1.f / 512.f) - mean * mean;
  float inv = rsqrtf(var + 1e-12f);
  float2 wv = *(const float2*)(w + tid * 2);
  float2 bv = *(const float2*)(bias + tid * 2);
  float ox = (vx - mean) * inv * wv.x + bv.x;
  float oy = (vy - mean) * inv * wv.y + bv.y;
  *(float2*)(hln + (size_t)bt * DMODEL + tid * 2) = make_float2(ox, oy);
  hbf[(size_t)bt * DMODEL + tid * 2] = f2bf(ox);
  hbf[(size_t)bt * DMODEL + tid * 2 + 1] = f2bf(oy);
}

// ---------------- out = layernorm(f2 + hln) ----------------
__global__ __launch_bounds__(256)
void final_ln(const float* __restrict__ f2, const float* __restrict__ hln,
              const float* __restrict__ w, const float* __restrict__ bias,
              float* __restrict__ outp) {
  const int bt = blockIdx.x;
  const int tid = threadIdx.x;
  const float2 a = *(const float2*)(f2 + (size_t)bt * DMODEL + tid * 2);
  const float2 h = *(const float2*)(hln + (size_t)bt * DMODEL + tid * 2);
  float vx = a.x + h.x;
  float vy = a.y + h.y;
  float2 sr = block_sum2_256(vx + vy, vx * vx + vy * vy);
  float mean = sr.x * (1.f / 512.f);
  float var = sr.y * (1.f / 512.f) - mean * mean;
  float inv = rsqrtf(var + 1e-12f);
  float2 wv = *(const float2*)(w + tid * 2);
  float2 bv = *(const float2*)(bias + tid * 2);
  *(float2*)(outp + (size_t)bt * DMODEL + tid * 2) =
      make_float2((vx - mean) * inv * wv.x + bv.x, (vy - mean) * inv * wv.y + bv.y);
}

extern "C" void kernel_launch(void* const* d_in, const int* in_sizes, int n_in,
                              void* d_out, int out_size, void* d_ws, size_t ws_size,
                              hipStream_t stream) {
  const float* item_emb   = (const float*)d_in[0];
  const float* in_proj_w  = (const float*)d_in[3];
  const float* conv_w     = (const float*)d_in[4];
  const float* conv_b     = (const float*)d_in[5];
  const float* dt_bias    = (const float*)d_in[6];
  const float* A_log      = (const float*)d_in[7];
  const float* Dp         = (const float*)d_in[8];
  const float* norm_w     = (const float*)d_in[9];
  const float* out_proj_w = (const float*)d_in[10];
  const float* ln_w       = (const float*)d_in[11];
  const float* ln_b       = (const float*)d_in[12];
  const float* w1         = (const float*)d_in[13];
  const float* b1         = (const float*)d_in[14];
  const float* w2         = (const float*)d_in[15];
  const float* b2         = (const float*)d_in[16];
  const float* fln_w      = (const float*)d_in[17];
  const float* fln_b      = (const float*)d_in[18];
  float* outp = (float*)d_out;
  char* ws = (char*)d_ws;

  // ---- workspace layout (bytes) ----
  const size_t o_ubf  = 0;                 // [8192,512]  bf16    8,388,608
  const size_t o_win  = 8388608;           // [2304,512]  bf16    2,359,296
  const size_t o_wout = 10747904;          // [512,1024]  bf16    1,048,576
  const size_t o_w1   = 11796480;          // [2048,512]  bf16    2,097,152
  const size_t o_w2   = 13893632;          // [512,2048]  bf16    2,097,152
  const size_t o_dtf  = 15990784;          // [128,1024]  f32       524,288
  const size_t o_dtb  = 16515072;
  const size_t o_zdt  = 17039360;          // [8192,16]   f32       524,288
  const size_t o_zxb  = 17563648;          // [8192,2192] bf16   35,913,728
  const size_t o_xcf  = 53477376;          // [8192,1152] bf16   18,874,368
  const size_t o_xcb  = 72351744;
  const size_t o_yf   = 91226112;          // [8192,1024] bf16   16,777,216
  const size_t o_yb   = 108003328;         //               end 124,780,544
  // phase-2 aliases (regions dead by the time these are written)
  const size_t o_gbf  = o_xcf;             // [16384,1024] bf16 33.5MB (xcf/xcb dead)
  const size_t o_mo   = o_zxb;             // [16384,512]  f32  (zxb dead after gate_rms)
  const size_t o_hln  = o_yf;              // [8192,512]   f32  (yf dead after gate_rms)
  const size_t o_hbf  = o_ubf;             // [8192,512]   bf16 (u_bf dead after in-proj)
  const size_t o_h1   = o_gbf;             // [8192,2048]  bf16 (gbf dead after out-proj)
  const size_t o_f2   = o_yb;              // [8192,512]   f32  (yb dead after gate_rms)

  unsigned short* u_bf  = (unsigned short*)(ws + o_ubf);
  unsigned short* winb  = (unsigned short*)(ws + o_win);
  unsigned short* woutb = (unsigned short*)(ws + o_wout);
  unsigned short* w1b   = (unsigned short*)(ws + o_w1);
  unsigned short* w2b   = (unsigned short*)(ws + o_w2);
  float* dtf = (float*)(ws + o_dtf);
  float* dtb = (float*)(ws + o_dtb);
  float* zdt = (float*)(ws + o_zdt);
  unsigned short* zxb = (unsigned short*)(ws + o_zxb);
  unsigned short* xcf = (unsigned short*)(ws + o_xcf);
  unsigned short* xcb = (unsigned short*)(ws + o_xcb);
  unsigned short* yf  = (unsigned short*)(ws + o_yf);
  unsigned short* yb  = (unsigned short*)(ws + o_yb);
  unsigned short* gbf = (unsigned short*)(ws + o_gbf);
  float* mo  = (float*)(ws + o_mo);
  float* hln = (float*)(ws + o_hln);
  unsigned short* hbf = (unsigned short*)(ws + o_hbf);
  unsigned short* h1b = (unsigned short*)(ws + o_h1);
  float* f2  = (float*)(ws + o_f2);

  // ---- bf16 conversions ----
  {
    int n = NTOK * DMODEL;
    cvt_bf16<<<(n + 255) / 256, 256, 0, stream>>>(item_emb, u_bf, n);
    cvt_bf16_pad<<<(DPROJP * DMODEL + 255) / 256, 256, 0, stream>>>(in_proj_w, winb, DPROJ, DMODEL, DPROJP);
    n = DMODEL * DINNER;
    cvt_bf16<<<(n + 255) / 256, 256, 0, stream>>>(out_proj_w, woutb, n);
    n = DFFN * DMODEL;
    cvt_bf16<<<(n + 255) / 256, 256, 0, stream>>>(w1, w1b, n);
    n = DMODEL * DFFN;
    cvt_bf16<<<(n + 255) / 256, 256, 0, stream>>>(w2, w2b, n);
  }

  // ---- in-proj: zxb[8192,2192](bf16) = u @ in_proj_w^T ; dt cols fp32 -> zdt ----
  gemm_bt<2, 128><<<dim3(DPROJP / 128, NTOK / 128), 256, 0, stream>>>(u_bf, winb, zxb, nullptr, zdt, DMODEL, DPROJ);

  // ---- dt (softplus) to [dir][(b*16+h)][t]; conv+silu both dirs, row-major bf16 ----
  dt_softplus<<<1024, 256, 0, stream>>>(zdt, dt_bias, dtf, dtb);
  conv_silu_bf<<<dim3(9, NBATCH, 4), 256, 0, stream>>>(zxb, conv_w, conv_b, xcf, xcb);

  // ---- chunked SSD: 256 blocks = (dir,b,h) ----
  ssd_chunk<<<256, 256, 0, stream>>>(xcf, xcb, dtf, dtb, A_log, Dp, yf, yb);

  // ---- gate + RMS norm -> bf16 [16384,1024] ----
  gate_rms<<<2 * NTOK, 256, 0, stream>>>(yf, yb, zxb, norm_w, gbf);

  // ---- out-proj: mo[16384,512] = g @ out_proj_w^T (BN=64 -> 1024 blocks) ----
  gemm_bt<0, 64><<<dim3(DMODEL / 64, 2 * NTOK / 128), 256, 0, stream>>>(gbf, woutb, mo, nullptr, nullptr, DINNER, DMODEL);

  // ---- combine + first layernorm ----
  combine_ln<<<NTOK, 256, 0, stream>>>(mo, item_emb, ln_w, ln_b, hln, hbf);

  // ---- FFN ----
  gemm_bt<1, 128><<<dim3(DFFN / 128, NTOK / 128), 256, 0, stream>>>(hbf, w1b, h1b, b1, nullptr, DMODEL, DFFN);
  gemm_bt<0, 64><<<dim3(DMODEL / 64, NTOK / 128), 256, 0, stream>>>(h1b, w2b, f2, b2, nullptr, DFFN, DMODEL);

  // ---- final layernorm -> d_out ----
  final_ln<<<NTOK, 256, 0, stream>>>(f2, hln, fln_w, fln_b, outp);

  (void)in_sizes; (void)n_in; (void)out_size; (void)ws_size;
}

// Round 7
// 416.641 us; speedup vs baseline: 1.3205x; 1.0826x over previous
//
#include <hip/hip_runtime.h>
#include <math.h>

#define SEQ     1024
#define NBATCH  8
#define NTOK    8192        // NBATCH*SEQ
#define DMODEL  512
#define DINNER  1024
#define NHEADS  16
#define DPROJ   2192
#define DPROJP  2304        // padded to multiple of 128
#define CONVDIM 1152
#define DFFN    2048

typedef short bf16x8 __attribute__((ext_vector_type(8)));
typedef float f32x4  __attribute__((ext_vector_type(4)));

__device__ inline unsigned short f2bf(float f) {
  union { float f; unsigned int u; } v; v.f = f;
  unsigned int u = v.u;
  return (unsigned short)((u + 0x7FFFu + ((u >> 16) & 1u)) >> 16);
}
__device__ inline float bf2f(unsigned short s) {
  union { unsigned int u; float f; } v; v.u = ((unsigned int)s) << 16;
  return v.f;
}

// async global->LDS, 16B per lane; lds base must be wave-uniform (lane*16 added by HW)
#define GLDS16(g, l)                                                         \
  __builtin_amdgcn_global_load_lds(                                          \
      (const __attribute__((address_space(1))) unsigned int*)(g),            \
      (__attribute__((address_space(3))) unsigned int*)(l), 16, 0, 0)

// ---------------- bf16 conversion ----------------
__global__ __launch_bounds__(256) void cvt_bf16(const float* __restrict__ s,
                                                unsigned short* __restrict__ d, int n) {
  int i = blockIdx.x * 256 + threadIdx.x;
  if (i < n) d[i] = f2bf(s[i]);
}

__global__ __launch_bounds__(256) void cvt_bf16_pad(const float* __restrict__ s,
                                                    unsigned short* __restrict__ d,
                                                    int realrows, int cols, int padrows) {
  int i = blockIdx.x * 256 + threadIdx.x;
  if (i < padrows * cols) {
    int r = i / cols;
    d[i] = (r < realrows) ? f2bf(s[i]) : (unsigned short)0;
  }
}

// ---------------- bf16 MFMA GEMM: C[M,N] = A[M,K] @ B[N,K]^T ----------------
// Single-barrier double-buffered global_load_lds pipeline. BM=128, BN in {128,64}.
template <int MODE, int BN>
__global__ __launch_bounds__(256)
void gemm_bt(const unsigned short* __restrict__ A, const unsigned short* __restrict__ B,
             void* __restrict__ Cout, const float* __restrict__ bias,
             float* __restrict__ aux, int K, int Nreal) {
  constexpr int NI = BN / 32;              // frags per wave in N: 4 or 2
  __shared__ unsigned short sA[2][128 * 32];
  __shared__ unsigned short sB[2][BN * 32];
  const int tid = threadIdx.x;
  const int bx = blockIdx.x, by = blockIdx.y;
  const int lane = tid & 63;
  const int wave = tid >> 6;
  const int wm = wave >> 1, wn = wave & 1;
  const int arow = tid >> 2;               // 0..63
  const int acol = (tid & 3) << 3;

  const unsigned short* pA = A + (size_t)(by * 128 + arow) * K + acol;
  const unsigned short* pB = B + (size_t)(bx * BN + arow) * K + acol;
  const size_t stride64 = (size_t)64 * K;
  char* sAw[2] = { (char*)&sA[0][0] + wave * 1024, (char*)&sA[1][0] + wave * 1024 };
  char* sBw[2] = { (char*)&sB[0][0] + wave * 1024, (char*)&sB[1][0] + wave * 1024 };

  f32x4 acc[4][NI];
#pragma unroll
  for (int i = 0; i < 4; i++)
#pragma unroll
    for (int j = 0; j < NI; j++) { f32x4 z = {0.f, 0.f, 0.f, 0.f}; acc[i][j] = z; }

  // prologue: stage k0=0 into buf 0
  GLDS16(pA, sAw[0]);
  GLDS16(pA + stride64, sAw[0] + 4096);
  GLDS16(pB, sBw[0]);
  if (BN == 128) GLDS16(pB + stride64, sBw[0] + 4096);
  pA += 32; pB += 32;
  __syncthreads();

  const int lrow = lane & 15;
  const int lkq = (lane >> 4) << 3;
  int cur = 0;
  for (int k0 = 0; k0 < K; k0 += 32) {
    if (k0 + 32 < K) {
      const int nxt = cur ^ 1;
      GLDS16(pA, sAw[nxt]);
      GLDS16(pA + stride64, sAw[nxt] + 4096);
      GLDS16(pB, sBw[nxt]);
      if (BN == 128) GLDS16(pB + stride64, sBw[nxt] + 4096);
      pA += 32; pB += 32;
    }
    bf16x8 af[4], bfr[NI];
#pragma unroll
    for (int mi = 0; mi < 4; mi++)
      af[mi] = *(const bf16x8*)&sA[cur][(wm * 64 + mi * 16 + lrow) * 32 + lkq];
#pragma unroll
    for (int ni = 0; ni < NI; ni++)
      bfr[ni] = *(const bf16x8*)&sB[cur][(wn * (BN / 2) + ni * 16 + lrow) * 32 + lkq];
#pragma unroll
    for (int mi = 0; mi < 4; mi++)
#pragma unroll
      for (int ni = 0; ni < NI; ni++)
        acc[mi][ni] = __builtin_amdgcn_mfma_f32_16x16x32_bf16(af[mi], bfr[ni], acc[mi][ni], 0, 0, 0);
    __syncthreads();
    cur ^= 1;
  }

  const int row0 = by * 128 + wm * 64;
  const int col0 = bx * BN + wn * (BN / 2);
#pragma unroll
  for (int mi = 0; mi < 4; mi++) {
#pragma unroll
    for (int ni = 0; ni < NI; ni++) {
      const int col = col0 + ni * 16 + lrow;
      if (col < Nreal) {
        const float bval = (MODE != 2 && bias) ? bias[col] : 0.f;
#pragma unroll
        for (int r = 0; r < 4; r++) {
          const int row = row0 + mi * 16 + ((lane >> 4) << 2) + r;
          float v = acc[mi][ni][r] + bval;
          if (MODE == 1) {
            float g = 0.5f * v * (1.f + erff(v * 0.7071067811865476f));
            ((unsigned short*)Cout)[(size_t)row * Nreal + col] = f2bf(g);
          } else if (MODE == 2) {
            ((unsigned short*)Cout)[(size_t)row * Nreal + col] = f2bf(v);
            if (col >= 2176) aux[(size_t)row * 16 + (col - 2176)] = v;
          } else {
            ((float*)Cout)[(size_t)row * Nreal + col] = v;
          }
        }
      }
    }
  }
}

// ---------------- dt = softplus(zdt + dt_bias); layout [dir][(b*16+h)][t] ----------------
__global__ __launch_bounds__(256)
void dt_softplus(const float* __restrict__ zdt, const float* __restrict__ dt_bias,
                 float* __restrict__ dtf, float* __restrict__ dtb) {
  int i = blockIdx.x * 256 + threadIdx.x;     // 0 .. 262143
  int dir = i >> 17;
  int rem = i & 131071;
  int row = rem >> 10;                        // b*16+h
  int t = rem & 1023;
  int b = row >> 4, h = row & 15;
  int srow = (b << 10) + (dir ? (1023 - t) : t);
  float v = zdt[(size_t)srow * 16 + h] + dt_bias[h];
  float dt = (v > 20.f) ? v : log1pf(expf(v));
  (dir ? dtb : dtf)[(row << 10) + t] = dt;
}

// ---------------- sliding-window causal dw-conv (k=4) + silu, BOTH dirs ----------------
// 32 time-segments of 32 steps (4.5 blocks/CU) for latency hiding.
__global__ __launch_bounds__(256)
void conv_silu_bf(const unsigned short* __restrict__ zxb, const float* __restrict__ cw,
                  const float* __restrict__ cb,
                  unsigned short* __restrict__ xcf, unsigned short* __restrict__ xcb) {
  const int tid = threadIdx.x;
  const int c = blockIdx.x * 128 + (tid & 127);     // channel 0..1151
  const int b = blockIdx.y;
  const int seg = blockIdx.z * 2 + (tid >> 7);      // 0..31 (32 steps each)
  const int t0 = seg << 5;
  const float w0 = cw[c * 4 + 0], w1 = cw[c * 4 + 1], w2 = cw[c * 4 + 2], w3 = cw[c * 4 + 3];
  const float bias = cb[c];
  const unsigned short* src = zxb + (size_t)(b << 10) * DPROJ + DINNER + c;
  unsigned short* dstf = xcf + (size_t)(b << 10) * CONVDIM + c;
  unsigned short* dstb = xcb + (size_t)(b << 10) * CONVDIM + c;
  float r0 = 0.f, r1 = 0.f, r2 = 0.f;               // rows s-3, s-2, s-1
  if (t0 >= 3) {
    r0 = bf2f(src[(size_t)(t0 - 3) * DPROJ]);
    r1 = bf2f(src[(size_t)(t0 - 2) * DPROJ]);
    r2 = bf2f(src[(size_t)(t0 - 1) * DPROJ]);
  }
  for (int s = t0; s < t0 + 32; s++) {
    float x = bf2f(src[(size_t)s * DPROJ]);
    float vf = bias + w0 * r0 + w1 * r1 + w2 * r2 + w3 * x;
    dstf[(size_t)s * CONVDIM] = f2bf(vf / (1.f + expf(-vf)));
    int tp = 1026 - s;
    if (tp <= 1023) {                               // s >= 3
      float vb = bias + w0 * x + w1 * r2 + w2 * r1 + w3 * r0;
      dstb[(size_t)tp * CONVDIM] = f2bf(vb / (1.f + expf(-vb)));
    }
    r0 = r1; r1 = r2; r2 = x;
  }
  if (seg == 31) {
    // window: r0=row1021, r1=row1022, r2=row1023; emit bwd t' = 2,1,0
    float v2 = bias + w1 * r2 + w2 * r1 + w3 * r0;
    float v1 = bias + w2 * r2 + w3 * r1;
    float v0 = bias + w3 * r2;
    dstb[(size_t)2 * CONVDIM] = f2bf(v2 / (1.f + expf(-v2)));
    dstb[(size_t)1 * CONVDIM] = f2bf(v1 / (1.f + expf(-v1)));
    dstb[0] = f2bf(v0 / (1.f + expf(-v0)));
  }
}

// ---------------- chunked SSD: one block per (dir,b,h), 16 chunks of L=64 ----------------
__global__ __launch_bounds__(256)
void ssd_chunk(const unsigned short* __restrict__ xcf, const unsigned short* __restrict__ xcb,
               const float* __restrict__ dtf, const float* __restrict__ dtb,
               const float* __restrict__ A_log, const float* __restrict__ Dp,
               unsigned short* __restrict__ yf, unsigned short* __restrict__ yb) {
  const int blk = blockIdx.x;
  const int dir = blk >> 7;
  const int b = (blk >> 4) & 7;
  const int h = blk & 15;
  const unsigned short* xc = dir ? xcb : xcf;
  const float* dts = (dir ? dtb : dtf) + ((size_t)((b << 4) + h) << 10);
  unsigned short* yo = dir ? yb : yf;
  const float A = -expf(A_log[h]);
  const float Dh = Dp[h];
  const int tid = threadIdx.x;
  const int lane = tid & 63;
  const int w = tid >> 6;
  const int lrow = lane & 15;
  const int quad = lane >> 4;
  const int lk8 = quad << 3;
  const int bS = b << 10;
  const int pr = tid & 31;          // channel pair for transpose staging
  const int sg = tid >> 5;          // s-group (8 timesteps)

  __shared__ unsigned short Cb[64 * 72];   // [s][n]  raw
  __shared__ unsigned short Bb[64 * 72];   // [s][n]  raw
  __shared__ unsigned short Xt[64 * 72];   // [p][s]  transposed
  __shared__ unsigned short Bt[64 * 72];   // [n][s]  transposed, * wv_s
  __shared__ unsigned short Mb[64 * 72];   // [i][s]  masked
  __shared__ unsigned short Hb[64 * 72];   // [p][n]  h_init
  __shared__ float sdt_all[1024];

  {
    float4 dv = *(const float4*)(dts + tid * 4);
    *(float4*)&sdt_all[tid * 4] = dv;
  }

  f32x4 hacc[4];
#pragma unroll
  for (int j = 0; j < 4; j++) { f32x4 z = {0.f, 0.f, 0.f, 0.f}; hacc[j] = z; }

  for (int c = 0; c < 16; c++) {
    const int t0 = c << 6;
    __syncthreads();                 // prev chunk's LDS readers done (covers sdt on c==0)

    float dtl = sdt_all[t0 + lane];
    float v = dtl;
#pragma unroll
    for (int off = 1; off < 64; off <<= 1) {
      float o = __shfl_up(v, off);
      if (lane >= off) v += o;
    }
    const float Lv = A * v;
    const float ev = expf(Lv);
    const float LL = __shfl(Lv, 63);
    const float wv = dtl * expf(LL - Lv);    // in (0, dt]: safe
    const float dtot = expf(LL);

    // stage h_init -> LDS
#pragma unroll
    for (int j = 0; j < 4; j++)
#pragma unroll
      for (int r = 0; r < 4; r++)
        Hb[(w * 16 + quad * 4 + r) * 72 + j * 16 + lrow] = f2bf(hacc[j][r]);

    // stage Bb/Cb rows (raw, coalesced uint4)
#pragma unroll
    for (int pass = 0; pass < 2; pass++) {
      int u = pass * 256 + tid;
      int sl = u >> 3, c8 = u & 7;
      const unsigned short* rowp = xc + (size_t)(bS + t0 + sl) * CONVDIM;
      uint4 vb = *(const uint4*)(rowp + 1024 + c8 * 8);
      uint4 vc = *(const uint4*)(rowp + 1088 + c8 * 8);
      *(uint4*)&Bb[sl * 72 + c8 * 8] = vb;
      *(uint4*)&Cb[sl * 72 + c8 * 8] = vc;
    }

    // stage Xt (raw) and Bt (* wv_s) via register transpose: 2 channels x 8 timesteps
    {
      unsigned int xv[8], bv[8];
      const unsigned short* base = xc + (size_t)(bS + t0 + sg * 8) * CONVDIM;
#pragma unroll
      for (int k = 0; k < 8; k++) {
        const unsigned short* rp = base + (size_t)k * CONVDIM;
        xv[k] = *(const unsigned int*)(rp + h * 64 + pr * 2);
        bv[k] = *(const unsigned int*)(rp + 1024 + pr * 2);
      }
      unsigned short x0[8], x1[8], b0[8], b1[8];
#pragma unroll
      for (int k = 0; k < 8; k++) {
        float ws = __shfl(wv, sg * 8 + k);
        x0[k] = (unsigned short)(xv[k] & 0xffff);
        x1[k] = (unsigned short)(xv[k] >> 16);
        b0[k] = f2bf(bf2f((unsigned short)(bv[k] & 0xffff)) * ws);
        b1[k] = f2bf(bf2f((unsigned short)(bv[k] >> 16)) * ws);
      }
      *(uint4*)&Xt[(pr * 2 + 0) * 72 + sg * 8] = *(const uint4*)x0;
      *(uint4*)&Xt[(pr * 2 + 1) * 72 + sg * 8] = *(const uint4*)x1;
      *(uint4*)&Bt[(pr * 2 + 0) * 72 + sg * 8] = *(const uint4*)b0;
      *(uint4*)&Bt[(pr * 2 + 1) * 72 + sg * 8] = *(const uint4*)b1;
    }
    __syncthreads();

    // GEMM1: M1[i][s] = C @ B^T (raw)
    f32x4 m1[4];
#pragma unroll
    for (int j = 0; j < 4; j++) { f32x4 z = {0.f, 0.f, 0.f, 0.f}; m1[j] = z; }
#pragma unroll
    for (int kq = 0; kq < 2; kq++) {
      bf16x8 af = *(const bf16x8*)&Cb[(w * 16 + lrow) * 72 + kq * 32 + lk8];
#pragma unroll
      for (int j = 0; j < 4; j++) {
        bf16x8 bf = *(const bf16x8*)&Bb[(j * 16 + lrow) * 72 + kq * 32 + lk8];
        m1[j] = __builtin_amdgcn_mfma_f32_16x16x32_bf16(af, bf, m1[j], 0, 0, 0);
      }
    }
    // mask + decay -> Mb
#pragma unroll
    for (int r = 0; r < 4; r++) {
      int i = w * 16 + quad * 4 + r;
      float Li = __shfl(Lv, i);
#pragma unroll
      for (int j = 0; j < 4; j++) {
        int s = j * 16 + lrow;
        float Ls = __shfl(Lv, s);
        float ds = __shfl(dtl, s);
        float val = (s <= i) ? m1[j][r] * expf(Li - Ls) * ds : 0.f;
        Mb[i * 72 + s] = f2bf(val);
      }
    }
    __syncthreads();

    // Y = M@X ; T = C@H^T ; S = Xt@Bt^T  (Bt already carries wv_s)
    f32x4 Y[4], T[4], S[4];
#pragma unroll
    for (int j = 0; j < 4; j++) {
      f32x4 z = {0.f, 0.f, 0.f, 0.f};
      Y[j] = z; T[j] = z; S[j] = z;
    }
#pragma unroll
    for (int kq = 0; kq < 2; kq++) {
      bf16x8 am = *(const bf16x8*)&Mb[(w * 16 + lrow) * 72 + kq * 32 + lk8];
      bf16x8 ac = *(const bf16x8*)&Cb[(w * 16 + lrow) * 72 + kq * 32 + lk8];
      bf16x8 ax = *(const bf16x8*)&Xt[(w * 16 + lrow) * 72 + kq * 32 + lk8];
#pragma unroll
      for (int j = 0; j < 4; j++) {
        bf16x8 bx = *(const bf16x8*)&Xt[(j * 16 + lrow) * 72 + kq * 32 + lk8];
        bf16x8 bh = *(const bf16x8*)&Hb[(j * 16 + lrow) * 72 + kq * 32 + lk8];
        bf16x8 bw = *(const bf16x8*)&Bt[(j * 16 + lrow) * 72 + kq * 32 + lk8];
        Y[j] = __builtin_amdgcn_mfma_f32_16x16x32_bf16(am, bx, Y[j], 0, 0, 0);
        T[j] = __builtin_amdgcn_mfma_f32_16x16x32_bf16(ac, bh, T[j], 0, 0, 0);
        S[j] = __builtin_amdgcn_mfma_f32_16x16x32_bf16(ax, bw, S[j], 0, 0, 0);
      }
    }

    // combine + store Y (bf16), update h
#pragma unroll
    for (int r = 0; r < 4; r++) {
      int i = w * 16 + quad * 4 + r;
      float ei = __shfl(ev, i);
#pragma unroll
      for (int j = 0; j < 4; j++) {
        int p = j * 16 + lrow;
        float yv = Y[j][r] + ei * T[j][r] + Dh * bf2f(Xt[p * 72 + i]);
        yo[(size_t)(bS + t0 + i) * DINNER + h * 64 + p] = f2bf(yv);
      }
    }
#pragma unroll
    for (int j = 0; j < 4; j++)
#pragma unroll
      for (int r = 0; r < 4; r++)
        hacc[j][r] = dtot * hacc[j][r] + S[j][r];
  }
}

// ---------------- block reduction (256 threads, 4 waves) ----------------
__device__ inline float2 block_sum2_256(float a, float b) {
#pragma unroll
  for (int o = 32; o >= 1; o >>= 1) { a += __shfl_xor(a, o); b += __shfl_xor(b, o); }
  __shared__ float ra[4], rb[4];
  const int lane = threadIdx.x & 63, w = threadIdx.x >> 6;
  if (lane == 0) { ra[w] = a; rb[w] = b; }
  __syncthreads();
  float2 out;
  out.x = ra[0] + ra[1] + ra[2] + ra[3];
  out.y = rb[0] + rb[1] + rb[2] + rb[3];
  return out;
}

// ---------------- g = y*silu(z); RMS-norm; -> bf16 ----------------
__global__ __launch_bounds__(256)
void gate_rms(const unsigned short* __restrict__ yf, const unsigned short* __restrict__ yb,
              const unsigned short* __restrict__ zxb, const float* __restrict__ nw,
              unsigned short* __restrict__ gbf) {
  const int r = blockIdx.x;          // 0..16383 (dir-major)
  const int dir = r >> 13;
  const int bt = r & (NTOK - 1);
  const int b = bt >> 10, t = bt & 1023;
  const int zrow = (b << 10) + (dir ? (1023 - t) : t);
  const unsigned short* y = (dir ? yb : yf) + (size_t)bt * DINNER;
  const unsigned short* z = zxb + (size_t)zrow * DPROJ;
  const int tid = threadIdx.x;
  ushort4 yv4 = *(const ushort4*)(y + tid * 4);
  ushort4 zv4 = *(const ushort4*)(z + tid * 4);
  float y0 = bf2f(yv4.x), y1 = bf2f(yv4.y), y2 = bf2f(yv4.z), y3 = bf2f(yv4.w);
  float z0 = bf2f(zv4.x), z1 = bf2f(zv4.y), z2 = bf2f(zv4.z), z3 = bf2f(zv4.w);
  float4 g;
  g.x = y0 * (z0 / (1.f + expf(-z0)));
  g.y = y1 * (z1 / (1.f + expf(-z1)));
  g.z = y2 * (z2 / (1.f + expf(-z2)));
  g.w = y3 * (z3 / (1.f + expf(-z3)));
  float2 sr = block_sum2_256(g.x * g.x + g.y * g.y + g.z * g.z + g.w * g.w, 0.f);
  float scale = rsqrtf(sr.x * (1.f / 1024.f) + 1e-5f);
  float4 wv = *(const float4*)(nw + tid * 4);
  unsigned short* o = gbf + (size_t)r * DINNER + tid * 4;
  o[0] = f2bf(g.x * scale * wv.x);
  o[1] = f2bf(g.y * scale * wv.y);
  o[2] = f2bf(g.z * scale * wv.z);
  o[3] = f2bf(g.w * scale * wv.w);
}

// ---------------- h = fwd + 0.5*bwd + u; layernorm -> fp32 + bf16 ----------------
__global__ __launch_bounds__(256)
void combine_ln(const float* __restrict__ mo, const float* __restrict__ u,
                const float* __restrict__ w, const float* __restrict__ bias,
                float* __restrict__ hln, unsigned short* __restrict__ hbf) {
  const int bt = blockIdx.x;
  const int tid = threadIdx.x;
  const float2 mf = *(const float2*)(mo + (size_t)bt * DMODEL + tid * 2);
  const float2 mb = *(const float2*)(mo + (size_t)(NTOK + bt) * DMODEL + tid * 2);
  const float2 uu = *(const float2*)(u + (size_t)bt * DMODEL + tid * 2);
  float vx = mf.x + 0.5f * mb.x + uu.x;
  float vy = mf.y + 0.5f * mb.y + uu.y;
  float2 sr = block_sum2_256(vx + vy, vx * vx + vy * vy);
  float mean = sr.x * (1.f / 512.f);
  float var = sr.y * (1.f / 512.f) - mean * mean;
  float inv = rsqrtf(var + 1e-12f);
  float2 wv = *(const float2*)(w + tid * 2);
  float2 bv = *(const float2*)(bias + tid * 2);
  float ox = (vx - mean) * inv * wv.x + bv.x;
  float oy = (vy - mean) * inv * wv.y + bv.y;
  *(float2*)(hln + (size_t)bt * DMODEL + tid * 2) = make_float2(ox, oy);
  hbf[(size_t)bt * DMODEL + tid * 2] = f2bf(ox);
  hbf[(size_t)bt * DMODEL + tid * 2 + 1] = f2bf(oy);
}

// ---------------- out = layernorm(f2 + hln) ----------------
__global__ __launch_bounds__(256)
void final_ln(const float* __restrict__ f2, const float* __restrict__ hln,
              const float* __restrict__ w, const float* __restrict__ bias,
              float* __restrict__ outp) {
  const int bt = blockIdx.x;
  const int tid = threadIdx.x;
  const float2 a = *(const float2*)(f2 + (size_t)bt * DMODEL + tid * 2);
  const float2 h = *(const float2*)(hln + (size_t)bt * DMODEL + tid * 2);
  float vx = a.x + h.x;
  float vy = a.y + h.y;
  float2 sr = block_sum2_256(vx + vy, vx * vx + vy * vy);
  float mean = sr.x * (1.f / 512.f);
  float var = sr.y * (1.f / 512.f) - mean * mean;
  float inv = rsqrtf(var + 1e-12f);
  float2 wv = *(const float2*)(w + tid * 2);
  float2 bv = *(const float2*)(bias + tid * 2);
  *(float2*)(outp + (size_t)bt * DMODEL + tid * 2) =
      make_float2((vx - mean) * inv * wv.x + bv.x, (vy - mean) * inv * wv.y + bv.y);
}

extern "C" void kernel_launch(void* const* d_in, const int* in_sizes, int n_in,
                              void* d_out, int out_size, void* d_ws, size_t ws_size,
                              hipStream_t stream) {
  const float* item_emb   = (const float*)d_in[0];
  const float* in_proj_w  = (const float*)d_in[3];
  const float* conv_w     = (const float*)d_in[4];
  const float* conv_b     = (const float*)d_in[5];
  const float* dt_bias    = (const float*)d_in[6];
  const float* A_log      = (const float*)d_in[7];
  const float* Dp         = (const float*)d_in[8];
  const float* norm_w     = (const float*)d_in[9];
  const float* out_proj_w = (const float*)d_in[10];
  const float* ln_w       = (const float*)d_in[11];
  const float* ln_b       = (const float*)d_in[12];
  const float* w1         = (const float*)d_in[13];
  const float* b1         = (const float*)d_in[14];
  const float* w2         = (const float*)d_in[15];
  const float* b2         = (const float*)d_in[16];
  const float* fln_w      = (const float*)d_in[17];
  const float* fln_b      = (const float*)d_in[18];
  float* outp = (float*)d_out;
  char* ws = (char*)d_ws;

  // ---- workspace layout (bytes) ----
  const size_t o_ubf  = 0;                 // [8192,512]  bf16    8,388,608
  const size_t o_win  = 8388608;           // [2304,512]  bf16    2,359,296
  const size_t o_wout = 10747904;          // [512,1024]  bf16    1,048,576
  const size_t o_w1   = 11796480;          // [2048,512]  bf16    2,097,152
  const size_t o_w2   = 13893632;          // [512,2048]  bf16    2,097,152
  const size_t o_dtf  = 15990784;          // [128,1024]  f32       524,288
  const size_t o_dtb  = 16515072;
  const size_t o_zdt  = 17039360;          // [8192,16]   f32       524,288
  const size_t o_zxb  = 17563648;          // [8192,2192] bf16   35,913,728
  const size_t o_xcf  = 53477376;          // [8192,1152] bf16   18,874,368
  const size_t o_xcb  = 72351744;
  const size_t o_yf   = 91226112;          // [8192,1024] bf16   16,777,216
  const size_t o_yb   = 108003328;         //               end 124,780,544
  // phase-2 aliases (regions dead by the time these are written)
  const size_t o_gbf  = o_xcf;             // [16384,1024] bf16 33.5MB (xcf/xcb dead)
  const size_t o_mo   = o_zxb;             // [16384,512]  f32  (zxb dead after gate_rms)
  const size_t o_hln  = o_yf;              // [8192,512]   f32  (yf dead after gate_rms)
  const size_t o_hbf  = o_ubf;             // [8192,512]   bf16 (u_bf dead after in-proj)
  const size_t o_h1   = o_gbf;             // [8192,2048]  bf16 (gbf dead after out-proj)
  const size_t o_f2   = o_yb;              // [8192,512]   f32  (yb dead after gate_rms)

  unsigned short* u_bf  = (unsigned short*)(ws + o_ubf);
  unsigned short* winb  = (unsigned short*)(ws + o_win);
  unsigned short* woutb = (unsigned short*)(ws + o_wout);
  unsigned short* w1b   = (unsigned short*)(ws + o_w1);
  unsigned short* w2b   = (unsigned short*)(ws + o_w2);
  float* dtf = (float*)(ws + o_dtf);
  float* dtb = (float*)(ws + o_dtb);
  float* zdt = (float*)(ws + o_zdt);
  unsigned short* zxb = (unsigned short*)(ws + o_zxb);
  unsigned short* xcf = (unsigned short*)(ws + o_xcf);
  unsigned short* xcb = (unsigned short*)(ws + o_xcb);
  unsigned short* yf  = (unsigned short*)(ws + o_yf);
  unsigned short* yb  = (unsigned short*)(ws + o_yb);
  unsigned short* gbf = (unsigned short*)(ws + o_gbf);
  float* mo  = (float*)(ws + o_mo);
  float* hln = (float*)(ws + o_hln);
  unsigned short* hbf = (unsigned short*)(ws + o_hbf);
  unsigned short* h1b = (unsigned short*)(ws + o_h1);
  float* f2  = (float*)(ws + o_f2);

  // ---- bf16 conversions ----
  {
    int n = NTOK * DMODEL;
    cvt_bf16<<<(n + 255) / 256, 256, 0, stream>>>(item_emb, u_bf, n);
    cvt_bf16_pad<<<(DPROJP * DMODEL + 255) / 256, 256, 0, stream>>>(in_proj_w, winb, DPROJ, DMODEL, DPROJP);
    n = DMODEL * DINNER;
    cvt_bf16<<<(n + 255) / 256, 256, 0, stream>>>(out_proj_w, woutb, n);
    n = DFFN * DMODEL;
    cvt_bf16<<<(n + 255) / 256, 256, 0, stream>>>(w1, w1b, n);
    n = DMODEL * DFFN;
    cvt_bf16<<<(n + 255) / 256, 256, 0, stream>>>(w2, w2b, n);
  }

  // ---- in-proj: zxb[8192,2192](bf16) = u @ in_proj_w^T ; dt cols fp32 -> zdt ----
  gemm_bt<2, 128><<<dim3(DPROJP / 128, NTOK / 128), 256, 0, stream>>>(u_bf, winb, zxb, nullptr, zdt, DMODEL, DPROJ);

  // ---- dt (softplus) to [dir][(b*16+h)][t]; conv+silu both dirs, 32 t-segments ----
  dt_softplus<<<1024, 256, 0, stream>>>(zdt, dt_bias, dtf, dtb);
  conv_silu_bf<<<dim3(9, NBATCH, 16), 256, 0, stream>>>(zxb, conv_w, conv_b, xcf, xcb);

  // ---- chunked SSD: 256 blocks = (dir,b,h) ----
  ssd_chunk<<<256, 256, 0, stream>>>(xcf, xcb, dtf, dtb, A_log, Dp, yf, yb);

  // ---- gate + RMS norm -> bf16 [16384,1024] ----
  gate_rms<<<2 * NTOK, 256, 0, stream>>>(yf, yb, zxb, norm_w, gbf);

  // ---- out-proj: mo[16384,512] = g @ out_proj_w^T (BN=64 -> 1024 blocks) ----
  gemm_bt<0, 64><<<dim3(DMODEL / 64, 2 * NTOK / 128), 256, 0, stream>>>(gbf, woutb, mo, nullptr, nullptr, DINNER, DMODEL);

  // ---- combine + first layernorm ----
  combine_ln<<<NTOK, 256, 0, stream>>>(mo, item_emb, ln_w, ln_b, hln, hbf);

  // ---- FFN ----
  gemm_bt<1, 128><<<dim3(DFFN / 128, NTOK / 128), 256, 0, stream>>>(hbf, w1b, h1b, b1, nullptr, DMODEL, DFFN);
  gemm_bt<0, 64><<<dim3(DMODEL / 64, NTOK / 128), 256, 0, stream>>>(h1b, w2b, f2, b2, nullptr, DFFN, DMODEL);

  // ---- final layernorm -> d_out ----
  final_ln<<<NTOK, 256, 0, stream>>>(f2, hln, fln_w, fln_b, outp);

  (void)in_sizes; (void)n_in; (void)out_size; (void)ws_size;
}

// Round 9
// 383.134 us; speedup vs baseline: 1.4360x; 1.0875x over previous
//
#include <hip/hip_runtime.h>
#include <math.h>

#define SEQ     1024
#define NBATCH  8
#define NTOK    8192        // NBATCH*SEQLEN
#define DMODEL  512
#define DINNER  1024
#define NHEADS  16
#define DPROJ   2192
#define DPROJP  2304        // padded to multiple of 128
#define CONVDIM 1152
#define DFFN    2048

typedef short bf16x8 __attribute__((ext_vector_type(8)));
typedef float f32x4  __attribute__((ext_vector_type(4)));

__device__ inline unsigned short f2bf(float f) {
  union { float f; unsigned int u; } v; v.f = f;
  unsigned int u = v.u;
  return (unsigned short)((u + 0x7FFFu + ((u >> 16) & 1u)) >> 16);
}
__device__ inline float bf2f(unsigned short s) {
  union { unsigned int u; float f; } v; v.u = ((unsigned int)s) << 16;
  return v.f;
}

// async global->LDS, 16B per lane; lds base must be wave-uniform (lane*16 added by HW)
#define GLDS16(g, l)                                                         \
  __builtin_amdgcn_global_load_lds(                                          \
      (const __attribute__((address_space(1))) unsigned int*)(g),            \
      (__attribute__((address_space(3))) unsigned int*)(l), 16, 0, 0)

// ---------------- bf16 conversion ----------------
__global__ __launch_bounds__(256) void cvt_bf16(const float* __restrict__ s,
                                                unsigned short* __restrict__ d, int n) {
  int i = blockIdx.x * 256 + threadIdx.x;
  if (i < n) d[i] = f2bf(s[i]);
}

__global__ __launch_bounds__(256) void cvt_bf16_pad(const float* __restrict__ s,
                                                    unsigned short* __restrict__ d,
                                                    int realrows, int cols, int padrows) {
  int i = blockIdx.x * 256 + threadIdx.x;
  if (i < padrows * cols) {
    int r = i / cols;
    d[i] = (r < realrows) ? f2bf(s[i]) : (unsigned short)0;
  }
}

// ---------------- bf16 MFMA GEMM: C[M,N] = A[M,K] @ B[N,K]^T ----------------
// 128x128 tile, 2x2 waves of 64x64, single-barrier double-buffered GLDS pipeline.
// blockIdx.z = split-K slice (Ksub cols; MODE-0 partial written at
// (float*)Cout + z*zstrideC; consumer sums). lda = full K stride of A and B.
template <int MODE>
__global__ __launch_bounds__(256)
void gemm_bt(const unsigned short* __restrict__ A, const unsigned short* __restrict__ B,
             void* __restrict__ Cout, const float* __restrict__ bias,
             float* __restrict__ aux, int Ksub, int lda, int Nreal, size_t zstrideC) {
  __shared__ unsigned short sA[2][128 * 32];
  __shared__ unsigned short sB[2][128 * 32];
  const int tid = threadIdx.x;
  const int bx = blockIdx.x, by = blockIdx.y, bz = blockIdx.z;
  const int lane = tid & 63;
  const int wave = tid >> 6;
  const int wm = wave >> 1, wn = wave & 1;
  const int arow = tid >> 2;               // 0..63
  const int acol = (tid & 3) << 3;

  const unsigned short* pA = A + (size_t)(by * 128 + arow) * lda + bz * Ksub + acol;
  const unsigned short* pB = B + (size_t)(bx * 128 + arow) * lda + bz * Ksub + acol;
  const size_t stride64 = (size_t)64 * lda;
  char* sAw[2] = { (char*)&sA[0][0] + wave * 1024, (char*)&sA[1][0] + wave * 1024 };
  char* sBw[2] = { (char*)&sB[0][0] + wave * 1024, (char*)&sB[1][0] + wave * 1024 };

  f32x4 acc[4][4];
#pragma unroll
  for (int i = 0; i < 4; i++)
#pragma unroll
    for (int j = 0; j < 4; j++) { f32x4 z = {0.f, 0.f, 0.f, 0.f}; acc[i][j] = z; }

  // prologue: stage k0=0 into buf 0
  GLDS16(pA, sAw[0]);
  GLDS16(pA + stride64, sAw[0] + 4096);
  GLDS16(pB, sBw[0]);
  GLDS16(pB + stride64, sBw[0] + 4096);
  pA += 32; pB += 32;
  __syncthreads();

  const int lrow = lane & 15;
  const int lkq = (lane >> 4) << 3;
  int cur = 0;
  for (int k0 = 0; k0 < Ksub; k0 += 32) {
    if (k0 + 32 < Ksub) {
      const int nxt = cur ^ 1;
      GLDS16(pA, sAw[nxt]);
      GLDS16(pA + stride64, sAw[nxt] + 4096);
      GLDS16(pB, sBw[nxt]);
      GLDS16(pB + stride64, sBw[nxt] + 4096);
      pA += 32; pB += 32;
    }
    bf16x8 af[4], bfr[4];
#pragma unroll
    for (int mi = 0; mi < 4; mi++)
      af[mi] = *(const bf16x8*)&sA[cur][(wm * 64 + mi * 16 + lrow) * 32 + lkq];
#pragma unroll
    for (int ni = 0; ni < 4; ni++)
      bfr[ni] = *(const bf16x8*)&sB[cur][(wn * 64 + ni * 16 + lrow) * 32 + lkq];
#pragma unroll
    for (int mi = 0; mi < 4; mi++)
#pragma unroll
      for (int ni = 0; ni < 4; ni++)
        acc[mi][ni] = __builtin_amdgcn_mfma_f32_16x16x32_bf16(af[mi], bfr[ni], acc[mi][ni], 0, 0, 0);
    __syncthreads();
    cur ^= 1;
  }

  const int row0 = by * 128 + wm * 64;
  const int col0 = bx * 128 + wn * 64;
  float* outf = (float*)Cout + (size_t)bz * zstrideC;
#pragma unroll
  for (int mi = 0; mi < 4; mi++) {
#pragma unroll
    for (int ni = 0; ni < 4; ni++) {
      const int col = col0 + ni * 16 + lrow;
      if (col < Nreal) {
        const float bval = (MODE != 2 && bias) ? bias[col] : 0.f;
#pragma unroll
        for (int r = 0; r < 4; r++) {
          const int row = row0 + mi * 16 + ((lane >> 4) << 2) + r;
          float v = acc[mi][ni][r] + bval;
          if (MODE == 1) {
            float g = 0.5f * v * (1.f + erff(v * 0.7071067811865476f));
            ((unsigned short*)Cout)[(size_t)row * Nreal + col] = f2bf(g);
          } else if (MODE == 2) {
            ((unsigned short*)Cout)[(size_t)row * Nreal + col] = f2bf(v);
            if (col >= 2176) aux[(size_t)row * 16 + (col - 2176)] = v;
          } else {
            outf[(size_t)row * Nreal + col] = v;
          }
        }
      }
    }
  }
}

// ---------------- dt = softplus(zdt + dt_bias); layout [dir][(b*16+h)][t] ----------------
__global__ __launch_bounds__(256)
void dt_softplus(const float* __restrict__ zdt, const float* __restrict__ dt_bias,
                 float* __restrict__ dtf, float* __restrict__ dtb) {
  int i = blockIdx.x * 256 + threadIdx.x;     // 0 .. 262143
  int dir = i >> 17;
  int rem = i & 131071;
  int row = rem >> 10;                        // b*16+h
  int t = rem & 1023;
  int b = row >> 4, h = row & 15;
  int srow = (b << 10) + (dir ? (1023 - t) : t);
  float v = zdt[(size_t)srow * 16 + h] + dt_bias[h];
  float dt = (v > 20.f) ? v : log1pf(expf(v));
  (dir ? dtb : dtf)[(row << 10) + t] = dt;
}

// ---------------- sliding-window causal dw-conv (k=4) + silu, BOTH dirs ----------------
__global__ __launch_bounds__(256)
void conv_silu_bf(const unsigned short* __restrict__ zxb, const float* __restrict__ cw,
                  const float* __restrict__ cb,
                  unsigned short* __restrict__ xcf, unsigned short* __restrict__ xcb) {
  const int tid = threadIdx.x;
  const int c = blockIdx.x * 128 + (tid & 127);     // channel 0..1151
  const int b = blockIdx.y;
  const int seg = blockIdx.z * 2 + (tid >> 7);      // 0..31 (32 steps each)
  const int t0 = seg << 5;
  const float w0 = cw[c * 4 + 0], w1 = cw[c * 4 + 1], w2 = cw[c * 4 + 2], w3 = cw[c * 4 + 3];
  const float bias = cb[c];
  const unsigned short* src = zxb + (size_t)(b << 10) * DPROJ + DINNER + c;
  unsigned short* dstf = xcf + (size_t)(b << 10) * CONVDIM + c;
  unsigned short* dstb = xcb + (size_t)(b << 10) * CONVDIM + c;
  float r0 = 0.f, r1 = 0.f, r2 = 0.f;               // rows s-3, s-2, s-1
  if (t0 >= 3) {
    r0 = bf2f(src[(size_t)(t0 - 3) * DPROJ]);
    r1 = bf2f(src[(size_t)(t0 - 2) * DPROJ]);
    r2 = bf2f(src[(size_t)(t0 - 1) * DPROJ]);
  }
  for (int s = t0; s < t0 + 32; s++) {
    float x = bf2f(src[(size_t)s * DPROJ]);
    float vf = bias + w0 * r0 + w1 * r1 + w2 * r2 + w3 * x;
    dstf[(size_t)s * CONVDIM] = f2bf(vf / (1.f + expf(-vf)));
    int tp = 1026 - s;
    if (tp <= 1023) {                               // s >= 3
      float vb = bias + w0 * x + w1 * r2 + w2 * r1 + w3 * r0;
      dstb[(size_t)tp * CONVDIM] = f2bf(vb / (1.f + expf(-vb)));
    }
    r0 = r1; r1 = r2; r2 = x;
  }
  if (seg == 31) {
    // window: r0=row1021, r1=row1022, r2=row1023; emit bwd t' = 2,1,0
    float v2 = bias + w1 * r2 + w2 * r1 + w3 * r0;
    float v1 = bias + w2 * r2 + w3 * r1;
    float v0 = bias + w3 * r2;
    dstb[(size_t)2 * CONVDIM] = f2bf(v2 / (1.f + expf(-v2)));
    dstb[(size_t)1 * CONVDIM] = f2bf(v1 / (1.f + expf(-v1)));
    dstb[0] = f2bf(v0 / (1.f + expf(-v0)));
  }
}

// ---------------- chunked SSD: one block per (dir,b,h), 16 chunks of L=64 ----------------
__global__ __launch_bounds__(256)
void ssd_chunk(const unsigned short* __restrict__ xcf, const unsigned short* __restrict__ xcb,
               const float* __restrict__ dtf, const float* __restrict__ dtb,
               const float* __restrict__ A_log, const float* __restrict__ Dp,
               unsigned short* __restrict__ yf, unsigned short* __restrict__ yb) {
  const int blk = blockIdx.x;
  const int dir = blk >> 7;
  const int b = (blk >> 4) & 7;
  const int h = blk & 15;
  const unsigned short* xc = dir ? xcb : xcf;
  const float* dts = (dir ? dtb : dtf) + ((size_t)((b << 4) + h) << 10);
  unsigned short* yo = dir ? yb : yf;
  const float A = -expf(A_log[h]);
  const float Dh = Dp[h];
  const int tid = threadIdx.x;
  const int lane = tid & 63;
  const int w = tid >> 6;
  const int lrow = lane & 15;
  const int quad = lane >> 4;
  const int lk8 = quad << 3;
  const int bS = b << 10;
  const int pr = tid & 31;          // channel pair for transpose staging
  const int sg = tid >> 5;          // s-group (8 timesteps)

  __shared__ unsigned short Cb[64 * 72];   // [s][n]  raw
  __shared__ unsigned short Bb[64 * 72];   // [s][n]  raw
  __shared__ unsigned short Xt[64 * 72];   // [p][s]  transposed
  __shared__ unsigned short Bt[64 * 72];   // [n][s]  transposed, * wv_s
  __shared__ unsigned short Mb[64 * 72];   // [i][s]  masked
  __shared__ unsigned short Hb[64 * 72];   // [p][n]  h_init
  __shared__ float sdt_all[1024];

  {
    float4 dv = *(const float4*)(dts + tid * 4);
    *(float4*)&sdt_all[tid * 4] = dv;
  }

  f32x4 hacc[4];
#pragma unroll
  for (int j = 0; j < 4; j++) { f32x4 z = {0.f, 0.f, 0.f, 0.f}; hacc[j] = z; }

  for (int c = 0; c < 16; c++) {
    const int t0 = c << 6;
    __syncthreads();                 // prev chunk's LDS readers done (covers sdt on c==0)

    float dtl = sdt_all[t0 + lane];
    float v = dtl;
#pragma unroll
    for (int off = 1; off < 64; off <<= 1) {
      float o = __shfl_up(v, off);
      if (lane >= off) v += o;
    }
    const float Lv = A * v;
    const float ev = expf(Lv);
    const float LL = __shfl(Lv, 63);
    const float wv = dtl * expf(LL - Lv);    // in (0, dt]: safe
    const float dtot = expf(LL);

    // stage h_init -> LDS
#pragma unroll
    for (int j = 0; j < 4; j++)
#pragma unroll
      for (int r = 0; r < 4; r++)
        Hb[(w * 16 + quad * 4 + r) * 72 + j * 16 + lrow] = f2bf(hacc[j][r]);

    // stage Bb/Cb rows (raw, coalesced uint4)
#pragma unroll
    for (int pass = 0; pass < 2; pass++) {
      int u = pass * 256 + tid;
      int sl = u >> 3, c8 = u & 7;
      const unsigned short* rowp = xc + (size_t)(bS + t0 + sl) * CONVDIM;
      uint4 vb = *(const uint4*)(rowp + 1024 + c8 * 8);
      uint4 vc = *(const uint4*)(rowp + 1088 + c8 * 8);
      *(uint4*)&Bb[sl * 72 + c8 * 8] = vb;
      *(uint4*)&Cb[sl * 72 + c8 * 8] = vc;
    }

    // stage Xt (raw) and Bt (* wv_s) via register transpose: 2 channels x 8 timesteps
    {
      unsigned int xv[8], bv[8];
      const unsigned short* base = xc + (size_t)(bS + t0 + sg * 8) * CONVDIM;
#pragma unroll
      for (int k = 0; k < 8; k++) {
        const unsigned short* rp = base + (size_t)k * CONVDIM;
        xv[k] = *(const unsigned int*)(rp + h * 64 + pr * 2);
        bv[k] = *(const unsigned int*)(rp + 1024 + pr * 2);
      }
      unsigned short x0[8], x1[8], b0[8], b1[8];
#pragma unroll
      for (int k = 0; k < 8; k++) {
        float ws = __shfl(wv, sg * 8 + k);
        x0[k] = (unsigned short)(xv[k] & 0xffff);
        x1[k] = (unsigned short)(xv[k] >> 16);
        b0[k] = f2bf(bf2f((unsigned short)(bv[k] & 0xffff)) * ws);
        b1[k] = f2bf(bf2f((unsigned short)(bv[k] >> 16)) * ws);
      }
      *(uint4*)&Xt[(pr * 2 + 0) * 72 + sg * 8] = *(const uint4*)x0;
      *(uint4*)&Xt[(pr * 2 + 1) * 72 + sg * 8] = *(const uint4*)x1;
      *(uint4*)&Bt[(pr * 2 + 0) * 72 + sg * 8] = *(const uint4*)b0;
      *(uint4*)&Bt[(pr * 2 + 1) * 72 + sg * 8] = *(const uint4*)b1;
    }
    __syncthreads();

    // GEMM1: M1[i][s] = C @ B^T (raw)
    f32x4 m1[4];
#pragma unroll
    for (int j = 0; j < 4; j++) { f32x4 z = {0.f, 0.f, 0.f, 0.f}; m1[j] = z; }
#pragma unroll
    for (int kq = 0; kq < 2; kq++) {
      bf16x8 af = *(const bf16x8*)&Cb[(w * 16 + lrow) * 72 + kq * 32 + lk8];
#pragma unroll
      for (int j = 0; j < 4; j++) {
        bf16x8 bf = *(const bf16x8*)&Bb[(j * 16 + lrow) * 72 + kq * 32 + lk8];
        m1[j] = __builtin_amdgcn_mfma_f32_16x16x32_bf16(af, bf, m1[j], 0, 0, 0);
      }
    }
    // mask + decay -> Mb
#pragma unroll
    for (int r = 0; r < 4; r++) {
      int i = w * 16 + quad * 4 + r;
      float Li = __shfl(Lv, i);
#pragma unroll
      for (int j = 0; j < 4; j++) {
        int s = j * 16 + lrow;
        float Ls = __shfl(Lv, s);
        float ds = __shfl(dtl, s);
        float val = (s <= i) ? m1[j][r] * expf(Li - Ls) * ds : 0.f;
        Mb[i * 72 + s] = f2bf(val);
      }
    }
    __syncthreads();

    // Y = M@X ; T = C@H^T ; S = Xt@Bt^T  (Bt already carries wv_s)
    f32x4 Y[4], T[4], S[4];
#pragma unroll
    for (int j = 0; j < 4; j++) {
      f32x4 z = {0.f, 0.f, 0.f, 0.f};
      Y[j] = z; T[j] = z; S[j] = z;
    }
#pragma unroll
    for (int kq = 0; kq < 2; kq++) {
      bf16x8 am = *(const bf16x8*)&Mb[(w * 16 + lrow) * 72 + kq * 32 + lk8];
      bf16x8 ac = *(const bf16x8*)&Cb[(w * 16 + lrow) * 72 + kq * 32 + lk8];
      bf16x8 ax = *(const bf16x8*)&Xt[(w * 16 + lrow) * 72 + kq * 32 + lk8];
#pragma unroll
      for (int j = 0; j < 4; j++) {
        bf16x8 bx = *(const bf16x8*)&Xt[(j * 16 + lrow) * 72 + kq * 32 + lk8];
        bf16x8 bh = *(const bf16x8*)&Hb[(j * 16 + lrow) * 72 + kq * 32 + lk8];
        bf16x8 bw = *(const bf16x8*)&Bt[(j * 16 + lrow) * 72 + kq * 32 + lk8];
        Y[j] = __builtin_amdgcn_mfma_f32_16x16x32_bf16(am, bx, Y[j], 0, 0, 0);
        T[j] = __builtin_amdgcn_mfma_f32_16x16x32_bf16(ac, bh, T[j], 0, 0, 0);
        S[j] = __builtin_amdgcn_mfma_f32_16x16x32_bf16(ax, bw, S[j], 0, 0, 0);
      }
    }

    // combine + store Y (bf16), update h
#pragma unroll
    for (int r = 0; r < 4; r++) {
      int i = w * 16 + quad * 4 + r;
      float ei = __shfl(ev, i);
#pragma unroll
      for (int j = 0; j < 4; j++) {
        int p = j * 16 + lrow;
        float yv = Y[j][r] + ei * T[j][r] + Dh * bf2f(Xt[p * 72 + i]);
        yo[(size_t)(bS + t0 + i) * DINNER + h * 64 + p] = f2bf(yv);
      }
    }
#pragma unroll
    for (int j = 0; j < 4; j++)
#pragma unroll
      for (int r = 0; r < 4; r++)
        hacc[j][r] = dtot * hacc[j][r] + S[j][r];
  }
}

// ---------------- block reduction (256 threads, 4 waves) ----------------
__device__ inline float2 block_sum2_256(float a, float b) {
#pragma unroll
  for (int o = 32; o >= 1; o >>= 1) { a += __shfl_xor(a, o); b += __shfl_xor(b, o); }
  __shared__ float ra[4], rb[4];
  const int lane = threadIdx.x & 63, w = threadIdx.x >> 6;
  if (lane == 0) { ra[w] = a; rb[w] = b; }
  __syncthreads();
  float2 out;
  out.x = ra[0] + ra[1] + ra[2] + ra[3];
  out.y = rb[0] + rb[1] + rb[2] + rb[3];
  return out;
}

// ---------------- combined gate+RMS for BOTH dirs -> comb = gn_f + 0.5*gn_b (bf16) ----
__global__ __launch_bounds__(256)
void gate_rms_comb(const unsigned short* __restrict__ yf, const unsigned short* __restrict__ yb,
                   const unsigned short* __restrict__ zxb, const float* __restrict__ nw,
                   unsigned short* __restrict__ comb) {
  const int bt = blockIdx.x;               // 0..8191 (fwd time == bwd row index)
  const int b = bt >> 10, t = bt & 1023;
  const int zrowb = (b << 10) + (1023 - t);
  const int tid = threadIdx.x;
  ushort4 yf4 = *(const ushort4*)(yf + (size_t)bt * DINNER + tid * 4);
  ushort4 yb4 = *(const ushort4*)(yb + (size_t)bt * DINNER + tid * 4);
  ushort4 zf4 = *(const ushort4*)(zxb + (size_t)bt * DPROJ + tid * 4);
  ushort4 zb4 = *(const ushort4*)(zxb + (size_t)zrowb * DPROJ + tid * 4);
  float gf[4], gb[4];
  {
    float z0 = bf2f(zf4.x), z1 = bf2f(zf4.y), z2 = bf2f(zf4.z), z3 = bf2f(zf4.w);
    gf[0] = bf2f(yf4.x) * (z0 / (1.f + expf(-z0)));
    gf[1] = bf2f(yf4.y) * (z1 / (1.f + expf(-z1)));
    gf[2] = bf2f(yf4.z) * (z2 / (1.f + expf(-z2)));
    gf[3] = bf2f(yf4.w) * (z3 / (1.f + expf(-z3)));
  }
  {
    float z0 = bf2f(zb4.x), z1 = bf2f(zb4.y), z2 = bf2f(zb4.z), z3 = bf2f(zb4.w);
    gb[0] = bf2f(yb4.x) * (z0 / (1.f + expf(-z0)));
    gb[1] = bf2f(yb4.y) * (z1 / (1.f + expf(-z1)));
    gb[2] = bf2f(yb4.z) * (z2 / (1.f + expf(-z2)));
    gb[3] = bf2f(yb4.w) * (z3 / (1.f + expf(-z3)));
  }
  float2 sr = block_sum2_256(gf[0]*gf[0] + gf[1]*gf[1] + gf[2]*gf[2] + gf[3]*gf[3],
                             gb[0]*gb[0] + gb[1]*gb[1] + gb[2]*gb[2] + gb[3]*gb[3]);
  float sf = rsqrtf(sr.x * (1.f / 1024.f) + 1e-5f);
  float sb = 0.5f * rsqrtf(sr.y * (1.f / 1024.f) + 1e-5f);
  float4 wv = *(const float4*)(nw + tid * 4);
  unsigned short* o = comb + (size_t)bt * DINNER + tid * 4;
  o[0] = f2bf((gf[0] * sf + gb[0] * sb) * wv.x);
  o[1] = f2bf((gf[1] * sf + gb[1] * sb) * wv.y);
  o[2] = f2bf((gf[2] * sf + gb[2] * sb) * wv.z);
  o[3] = f2bf((gf[3] * sf + gb[3] * sb) * wv.w);
}

// ---------------- h = (mo0+mo1) + u; layernorm -> fp32 + bf16 ----------------
__global__ __launch_bounds__(256)
void combine_ln(const float* __restrict__ mo0, const float* __restrict__ mo1,
                const float* __restrict__ u,
                const float* __restrict__ w, const float* __restrict__ bias,
                float* __restrict__ hln, unsigned short* __restrict__ hbf) {
  const int bt = blockIdx.x;
  const int tid = threadIdx.x;
  const float2 m0 = *(const float2*)(mo0 + (size_t)bt * DMODEL + tid * 2);
  const float2 m1 = *(const float2*)(mo1 + (size_t)bt * DMODEL + tid * 2);
  const float2 uu = *(const float2*)(u + (size_t)bt * DMODEL + tid * 2);
  float vx = m0.x + m1.x + uu.x;
  float vy = m0.y + m1.y + uu.y;
  float2 sr = block_sum2_256(vx + vy, vx * vx + vy * vy);
  float mean = sr.x * (1.f / 512.f);
  float var = sr.y * (1.f / 512.f) - mean * mean;
  float inv = rsqrtf(var + 1e-12f);
  float2 wv = *(const float2*)(w + tid * 2);
  float2 bv = *(const float2*)(bias + tid * 2);
  float ox = (vx - mean) * inv * wv.x + bv.x;
  float oy = (vy - mean) * inv * wv.y + bv.y;
  *(float2*)(hln + (size_t)bt * DMODEL + tid * 2) = make_float2(ox, oy);
  hbf[(size_t)bt * DMODEL + tid * 2] = f2bf(ox);
  hbf[(size_t)bt * DMODEL + tid * 2 + 1] = f2bf(oy);
}

// ---------------- out = layernorm(f2a + f2b + b2 + hln) ----------------
__global__ __launch_bounds__(256)
void final_ln(const float* __restrict__ f2a, const float* __restrict__ f2b,
              const float* __restrict__ b2, const float* __restrict__ hln,
              const float* __restrict__ w, const float* __restrict__ bias,
              float* __restrict__ outp) {
  const int bt = blockIdx.x;
  const int tid = threadIdx.x;
  const float2 a = *(const float2*)(f2a + (size_t)bt * DMODEL + tid * 2);
  const float2 bpart = *(const float2*)(f2b + (size_t)bt * DMODEL + tid * 2);
  const float2 bb = *(const float2*)(b2 + tid * 2);
  const float2 h = *(const float2*)(hln + (size_t)bt * DMODEL + tid * 2);
  float vx = a.x + bpart.x + bb.x + h.x;
  float vy = a.y + bpart.y + bb.y + h.y;
  float2 sr = block_sum2_256(vx + vy, vx * vx + vy * vy);
  float mean = sr.x * (1.f / 512.f);
  float var = sr.y * (1.f / 512.f) - mean * mean;
  float inv = rsqrtf(var + 1e-12f);
  float2 wv = *(const float2*)(w + tid * 2);
  float2 bv = *(const float2*)(bias + tid * 2);
  *(float2*)(outp + (size_t)bt * DMODEL + tid * 2) =
      make_float2((vx - mean) * inv * wv.x + bv.x, (vy - mean) * inv * wv.y + bv.y);
}

extern "C" void kernel_launch(void* const* d_in, const int* in_sizes, int n_in,
                              void* d_out, int out_size, void* d_ws, size_t ws_size,
                              hipStream_t stream) {
  const float* item_emb   = (const float*)d_in[0];
  const float* in_proj_w  = (const float*)d_in[3];
  const float* conv_w     = (const float*)d_in[4];
  const float* conv_b     = (const float*)d_in[5];
  const float* dt_bias    = (const float*)d_in[6];
  const float* A_log      = (const float*)d_in[7];
  const float* Dp         = (const float*)d_in[8];
  const float* norm_w     = (const float*)d_in[9];
  const float* out_proj_w = (const float*)d_in[10];
  const float* ln_w       = (const float*)d_in[11];
  const float* ln_b       = (const float*)d_in[12];
  const float* w1         = (const float*)d_in[13];
  const float* b1         = (const float*)d_in[14];
  const float* w2         = (const float*)d_in[15];
  const float* b2         = (const float*)d_in[16];
  const float* fln_w      = (const float*)d_in[17];
  const float* fln_b      = (const float*)d_in[18];
  float* outp = (float*)d_out;
  char* ws = (char*)d_ws;

  // ---- workspace layout (bytes) ----
  const size_t o_ubf  = 0;                 // [8192,512]  bf16    8,388,608
  const size_t o_win  = 8388608;           // [2304,512]  bf16    2,359,296
  const size_t o_wout = 10747904;          // [512,1024]  bf16    1,048,576
  const size_t o_w1   = 11796480;          // [2048,512]  bf16    2,097,152
  const size_t o_w2   = 13893632;          // [512,2048]  bf16    2,097,152
  const size_t o_dtf  = 15990784;          // [128,1024]  f32       524,288
  const size_t o_dtb  = 16515072;
  const size_t o_zdt  = 17039360;          // [8192,16]   f32       524,288
  const size_t o_zxb  = 17563648;          // [8192,2192] bf16   35,913,728
  const size_t o_xcf  = 53477376;          // [8192,1152] bf16   18,874,368
  const size_t o_xcb  = 72351744;          // [8192,1152] bf16   18,874,368
  const size_t o_yf   = 91226112;          // [8192,1024] bf16   16,777,216
  const size_t o_yb   = 108003328;         //               end 124,780,544
  // phase-2 aliases (regions dead by the time these are written)
  const size_t o_comb = o_xcf;             // [8192,1024] bf16 (xcf dead after ssd)
  const size_t o_mo0  = o_zxb;             // [8192,512]  f32  (zxb dead after gate_rms_comb)
  const size_t o_mo1  = o_zxb + 16777216;  // [8192,512]  f32  = mo0 + NTOK*DMODEL floats
  const size_t o_hln  = o_yb;              // [8192,512]  f32  (yb dead after gate_rms_comb)
  const size_t o_hbf  = o_ubf;             // [8192,512]  bf16 (u_bf dead after in-proj)
  const size_t o_h1   = o_xcb;             // [8192,2048] bf16 33.6MB (xcb+yf dead)
  const size_t o_f2a  = o_mo0;             // [8192,512]  f32  (mo dead after combine_ln)
  const size_t o_f2b  = o_mo1;             // = f2a + NTOK*DMODEL floats (zstrideC-consistent)

  unsigned short* u_bf  = (unsigned short*)(ws + o_ubf);
  unsigned short* winb  = (unsigned short*)(ws + o_win);
  unsigned short* woutb = (unsigned short*)(ws + o_wout);
  unsigned short* w1b   = (unsigned short*)(ws + o_w1);
  unsigned short* w2b   = (unsigned short*)(ws + o_w2);
  float* dtf = (float*)(ws + o_dtf);
  float* dtb = (float*)(ws + o_dtb);
  float* zdt = (float*)(ws + o_zdt);
  unsigned short* zxb = (unsigned short*)(ws + o_zxb);
  unsigned short* xcf = (unsigned short*)(ws + o_xcf);
  unsigned short* xcb = (unsigned short*)(ws + o_xcb);
  unsigned short* yf  = (unsigned short*)(ws + o_yf);
  unsigned short* yb  = (unsigned short*)(ws + o_yb);
  unsigned short* comb = (unsigned short*)(ws + o_comb);
  float* mo0 = (float*)(ws + o_mo0);
  float* mo1 = (float*)(ws + o_mo1);
  float* hln = (float*)(ws + o_hln);
  unsigned short* hbf = (unsigned short*)(ws + o_hbf);
  unsigned short* h1b = (unsigned short*)(ws + o_h1);
  float* f2a = (float*)(ws + o_f2a);
  float* f2b = (float*)(ws + o_f2b);

  // ---- bf16 conversions ----
  {
    int n = NTOK * DMODEL;
    cvt_bf16<<<(n + 255) / 256, 256, 0, stream>>>(item_emb, u_bf, n);
    cvt_bf16_pad<<<(DPROJP * DMODEL + 255) / 256, 256, 0, stream>>>(in_proj_w, winb, DPROJ, DMODEL, DPROJP);
    n = DMODEL * DINNER;
    cvt_bf16<<<(n + 255) / 256, 256, 0, stream>>>(out_proj_w, woutb, n);
    n = DFFN * DMODEL;
    cvt_bf16<<<(n + 255) / 256, 256, 0, stream>>>(w1, w1b, n);
    n = DMODEL * DFFN;
    cvt_bf16<<<(n + 255) / 256, 256, 0, stream>>>(w2, w2b, n);
  }

  // ---- in-proj: zxb[8192,2192](bf16) = u @ in_proj_w^T ; dt cols fp32 -> zdt ----
  gemm_bt<2><<<dim3(DPROJP / 128, NTOK / 128), 256, 0, stream>>>(
      u_bf, winb, zxb, nullptr, zdt, DMODEL, DMODEL, DPROJ, 0);

  // ---- dt (softplus) to [dir][(b*16+h)][t]; conv+silu both dirs ----
  dt_softplus<<<1024, 256, 0, stream>>>(zdt, dt_bias, dtf, dtb);
  conv_silu_bf<<<dim3(9, NBATCH, 16), 256, 0, stream>>>(zxb, conv_w, conv_b, xcf, xcb);

  // ---- chunked SSD: 256 blocks = (dir,b,h) ----
  ssd_chunk<<<256, 256, 0, stream>>>(xcf, xcb, dtf, dtb, A_log, Dp, yf, yb);

  // ---- fused gate + RMS + dir-combine -> comb[8192,1024] bf16 ----
  gate_rms_comb<<<NTOK, 256, 0, stream>>>(yf, yb, zxb, norm_w, comb);

  // ---- out-proj: mo = comb @ out_proj_w^T, split-K=2 (partials mo0/mo1) ----
  gemm_bt<0><<<dim3(DMODEL / 128, NTOK / 128, 2), 256, 0, stream>>>(
      comb, woutb, mo0, nullptr, nullptr, DINNER / 2, DINNER, DMODEL,
      (size_t)NTOK * DMODEL);

  // ---- combine + first layernorm ----
  combine_ln<<<NTOK, 256, 0, stream>>>(mo0, mo1, item_emb, ln_w, ln_b, hln, hbf);

  // ---- FFN1: h1 = gelu(hln @ w1^T + b1) -> bf16 ----
  gemm_bt<1><<<dim3(DFFN / 128, NTOK / 128), 256, 0, stream>>>(
      hbf, w1b, h1b, b1, nullptr, DMODEL, DMODEL, DFFN, 0);

  // ---- FFN2: f2 = h1 @ w2^T, split-K=2 (partials f2a/f2b; bias b2 in final_ln) ----
  gemm_bt<0><<<dim3(DMODEL / 128, NTOK / 128, 2), 256, 0, stream>>>(
      h1b, w2b, f2a, nullptr, nullptr, DFFN / 2, DFFN, DMODEL,
      (size_t)NTOK * DMODEL);

  // ---- final layernorm -> d_out ----
  final_ln<<<NTOK, 256, 0, stream>>>(f2a, f2b, b2, hln, fln_w, fln_b, outp);

  (void)in_sizes; (void)n_in; (void)out_size; (void)ws_size;
}

// Round 10
// 382.535 us; speedup vs baseline: 1.4383x; 1.0016x over previous
//
#include <hip/hip_runtime.h>
#include <math.h>

#define SEQ     1024
#define NBATCH  8
#define NTOK    8192        // NBATCH*SEQLEN
#define DMODEL  512
#define DINNER  1024
#define NHEADS  16
#define DPROJ   2192
#define DPROJP  2304        // padded to multiple of 128
#define CONVDIM 1152
#define DFFN    2048

typedef short bf16x8 __attribute__((ext_vector_type(8)));
typedef float f32x4  __attribute__((ext_vector_type(4)));

__device__ inline unsigned short f2bf(float f) {
  union { float f; unsigned int u; } v; v.f = f;
  unsigned int u = v.u;
  return (unsigned short)((u + 0x7FFFu + ((u >> 16) & 1u)) >> 16);
}
__device__ inline float bf2f(unsigned short s) {
  union { unsigned int u; float f; } v; v.u = ((unsigned int)s) << 16;
  return v.f;
}

// async global->LDS, 16B per lane; lds base must be wave-uniform (lane*16 added by HW)
#define GLDS16(g, l)                                                         \
  __builtin_amdgcn_global_load_lds(                                          \
      (const __attribute__((address_space(1))) unsigned int*)(g),            \
      (__attribute__((address_space(3))) unsigned int*)(l), 16, 0, 0)

// ---------------- bf16 conversion ----------------
__global__ __launch_bounds__(256) void cvt_bf16(const float* __restrict__ s,
                                                unsigned short* __restrict__ d, int n) {
  int i = blockIdx.x * 256 + threadIdx.x;
  if (i < n) d[i] = f2bf(s[i]);
}

__global__ __launch_bounds__(256) void cvt_bf16_pad(const float* __restrict__ s,
                                                    unsigned short* __restrict__ d,
                                                    int realrows, int cols, int padrows) {
  int i = blockIdx.x * 256 + threadIdx.x;
  if (i < padrows * cols) {
    int r = i / cols;
    d[i] = (r < realrows) ? f2bf(s[i]) : (unsigned short)0;
  }
}

// ---------------- bf16 MFMA GEMM: C[M,N] = A[M,K] @ B[N,K]^T ----------------
// 128x128 tile, 2x2 waves of 64x64, single-barrier double-buffered GLDS pipeline.
// blockIdx.z = split-K slice (Ksub cols). lda = full K stride of A and B.
// MODE 0: fp32 (+bias). MODE 1: bias+gelu->bf16. MODE 2: bf16, cols>=2176 also
// fp32 -> aux. MODE 3: bf16 PARTIAL at (ushort*)Cout + z*zstrideC (consumer sums).
template <int MODE>
__global__ __launch_bounds__(256)
void gemm_bt(const unsigned short* __restrict__ A, const unsigned short* __restrict__ B,
             void* __restrict__ Cout, const float* __restrict__ bias,
             float* __restrict__ aux, int Ksub, int lda, int Nreal, size_t zstrideC) {
  __shared__ unsigned short sA[2][128 * 32];
  __shared__ unsigned short sB[2][128 * 32];
  const int tid = threadIdx.x;
  const int bx = blockIdx.x, by = blockIdx.y, bz = blockIdx.z;
  const int lane = tid & 63;
  const int wave = tid >> 6;
  const int wm = wave >> 1, wn = wave & 1;
  const int arow = tid >> 2;               // 0..63
  const int acol = (tid & 3) << 3;

  const unsigned short* pA = A + (size_t)(by * 128 + arow) * lda + bz * Ksub + acol;
  const unsigned short* pB = B + (size_t)(bx * 128 + arow) * lda + bz * Ksub + acol;
  const size_t stride64 = (size_t)64 * lda;
  char* sAw[2] = { (char*)&sA[0][0] + wave * 1024, (char*)&sA[1][0] + wave * 1024 };
  char* sBw[2] = { (char*)&sB[0][0] + wave * 1024, (char*)&sB[1][0] + wave * 1024 };

  f32x4 acc[4][4];
#pragma unroll
  for (int i = 0; i < 4; i++)
#pragma unroll
    for (int j = 0; j < 4; j++) { f32x4 z = {0.f, 0.f, 0.f, 0.f}; acc[i][j] = z; }

  // prologue: stage k0=0 into buf 0
  GLDS16(pA, sAw[0]);
  GLDS16(pA + stride64, sAw[0] + 4096);
  GLDS16(pB, sBw[0]);
  GLDS16(pB + stride64, sBw[0] + 4096);
  pA += 32; pB += 32;
  __syncthreads();

  const int lrow = lane & 15;
  const int lkq = (lane >> 4) << 3;
  int cur = 0;
  for (int k0 = 0; k0 < Ksub; k0 += 32) {
    if (k0 + 32 < Ksub) {
      const int nxt = cur ^ 1;
      GLDS16(pA, sAw[nxt]);
      GLDS16(pA + stride64, sAw[nxt] + 4096);
      GLDS16(pB, sBw[nxt]);
      GLDS16(pB + stride64, sBw[nxt] + 4096);
      pA += 32; pB += 32;
    }
    bf16x8 af[4], bfr[4];
#pragma unroll
    for (int mi = 0; mi < 4; mi++)
      af[mi] = *(const bf16x8*)&sA[cur][(wm * 64 + mi * 16 + lrow) * 32 + lkq];
#pragma unroll
    for (int ni = 0; ni < 4; ni++)
      bfr[ni] = *(const bf16x8*)&sB[cur][(wn * 64 + ni * 16 + lrow) * 32 + lkq];
#pragma unroll
    for (int mi = 0; mi < 4; mi++)
#pragma unroll
      for (int ni = 0; ni < 4; ni++)
        acc[mi][ni] = __builtin_amdgcn_mfma_f32_16x16x32_bf16(af[mi], bfr[ni], acc[mi][ni], 0, 0, 0);
    __syncthreads();
    cur ^= 1;
  }

  const int row0 = by * 128 + wm * 64;
  const int col0 = bx * 128 + wn * 64;
  float* outf = (float*)Cout;
  unsigned short* outp16 = (unsigned short*)Cout + (size_t)bz * zstrideC;
#pragma unroll
  for (int mi = 0; mi < 4; mi++) {
#pragma unroll
    for (int ni = 0; ni < 4; ni++) {
      const int col = col0 + ni * 16 + lrow;
      if (col < Nreal) {
        const float bval = (MODE == 0 || MODE == 1) && bias ? bias[col] : 0.f;
#pragma unroll
        for (int r = 0; r < 4; r++) {
          const int row = row0 + mi * 16 + ((lane >> 4) << 2) + r;
          float v = acc[mi][ni][r] + bval;
          if (MODE == 1) {
            float g = 0.5f * v * (1.f + erff(v * 0.7071067811865476f));
            ((unsigned short*)Cout)[(size_t)row * Nreal + col] = f2bf(g);
          } else if (MODE == 2) {
            ((unsigned short*)Cout)[(size_t)row * Nreal + col] = f2bf(v);
            if (col >= 2176) aux[(size_t)row * 16 + (col - 2176)] = v;
          } else if (MODE == 3) {
            outp16[(size_t)row * Nreal + col] = f2bf(v);
          } else {
            outf[(size_t)row * Nreal + col] = v;
          }
        }
      }
    }
  }
}

// ---------------- dt = softplus(zdt + dt_bias); layout [dir][(b*16+h)][t] ----------------
__global__ __launch_bounds__(256)
void dt_softplus(const float* __restrict__ zdt, const float* __restrict__ dt_bias,
                 float* __restrict__ dtf, float* __restrict__ dtb) {
  int i = blockIdx.x * 256 + threadIdx.x;     // 0 .. 262143
  int dir = i >> 17;
  int rem = i & 131071;
  int row = rem >> 10;                        // b*16+h
  int t = rem & 1023;
  int b = row >> 4, h = row & 15;
  int srow = (b << 10) + (dir ? (1023 - t) : t);
  float v = zdt[(size_t)srow * 16 + h] + dt_bias[h];
  float dt = (v > 20.f) ? v : log1pf(expf(v));
  (dir ? dtb : dtf)[(row << 10) + t] = dt;
}

// ---------------- sliding-window causal dw-conv (k=4) + silu, BOTH dirs ----------------
__global__ __launch_bounds__(256)
void conv_silu_bf(const unsigned short* __restrict__ zxb, const float* __restrict__ cw,
                  const float* __restrict__ cb,
                  unsigned short* __restrict__ xcf, unsigned short* __restrict__ xcb) {
  const int tid = threadIdx.x;
  const int c = blockIdx.x * 128 + (tid & 127);     // channel 0..1151
  const int b = blockIdx.y;
  const int seg = blockIdx.z * 2 + (tid >> 7);      // 0..31 (32 steps each)
  const int t0 = seg << 5;
  const float w0 = cw[c * 4 + 0], w1 = cw[c * 4 + 1], w2 = cw[c * 4 + 2], w3 = cw[c * 4 + 3];
  const float bias = cb[c];
  const unsigned short* src = zxb + (size_t)(b << 10) * DPROJ + DINNER + c;
  unsigned short* dstf = xcf + (size_t)(b << 10) * CONVDIM + c;
  unsigned short* dstb = xcb + (size_t)(b << 10) * CONVDIM + c;
  float r0 = 0.f, r1 = 0.f, r2 = 0.f;               // rows s-3, s-2, s-1
  if (t0 >= 3) {
    r0 = bf2f(src[(size_t)(t0 - 3) * DPROJ]);
    r1 = bf2f(src[(size_t)(t0 - 2) * DPROJ]);
    r2 = bf2f(src[(size_t)(t0 - 1) * DPROJ]);
  }
  for (int s = t0; s < t0 + 32; s++) {
    float x = bf2f(src[(size_t)s * DPROJ]);
    float vf = bias + w0 * r0 + w1 * r1 + w2 * r2 + w3 * x;
    dstf[(size_t)s * CONVDIM] = f2bf(vf / (1.f + expf(-vf)));
    int tp = 1026 - s;
    if (tp <= 1023) {                               // s >= 3
      float vb = bias + w0 * x + w1 * r2 + w2 * r1 + w3 * r0;
      dstb[(size_t)tp * CONVDIM] = f2bf(vb / (1.f + expf(-vb)));
    }
    r0 = r1; r1 = r2; r2 = x;
  }
  if (seg == 31) {
    // window: r0=row1021, r1=row1022, r2=row1023; emit bwd t' = 2,1,0
    float v2 = bias + w1 * r2 + w2 * r1 + w3 * r0;
    float v1 = bias + w2 * r2 + w3 * r1;
    float v0 = bias + w3 * r2;
    dstb[(size_t)2 * CONVDIM] = f2bf(v2 / (1.f + expf(-v2)));
    dstb[(size_t)1 * CONVDIM] = f2bf(v1 / (1.f + expf(-v1)));
    dstb[0] = f2bf(v0 / (1.f + expf(-v0)));
  }
}

// ---------------- chunked SSD: one block per (dir,b,h), 16 chunks of L=64 ----------------
__global__ __launch_bounds__(256)
void ssd_chunk(const unsigned short* __restrict__ xcf, const unsigned short* __restrict__ xcb,
               const float* __restrict__ dtf, const float* __restrict__ dtb,
               const float* __restrict__ A_log, const float* __restrict__ Dp,
               unsigned short* __restrict__ yf, unsigned short* __restrict__ yb) {
  const int blk = blockIdx.x;
  const int dir = blk >> 7;
  const int b = (blk >> 4) & 7;
  const int h = blk & 15;
  const unsigned short* xc = dir ? xcb : xcf;
  const float* dts = (dir ? dtb : dtf) + ((size_t)((b << 4) + h) << 10);
  unsigned short* yo = dir ? yb : yf;
  const float A = -expf(A_log[h]);
  const float Dh = Dp[h];
  const int tid = threadIdx.x;
  const int lane = tid & 63;
  const int w = tid >> 6;
  const int lrow = lane & 15;
  const int quad = lane >> 4;
  const int lk8 = quad << 3;
  const int bS = b << 10;
  const int pr = tid & 31;          // channel pair for transpose staging
  const int sg = tid >> 5;          // s-group (8 timesteps)

  __shared__ unsigned short Cb[64 * 72];   // [s][n]  raw
  __shared__ unsigned short Bb[64 * 72];   // [s][n]  raw
  __shared__ unsigned short Xt[64 * 72];   // [p][s]  transposed
  __shared__ unsigned short Bt[64 * 72];   // [n][s]  transposed, * wv_s
  __shared__ unsigned short Mb[64 * 72];   // [i][s]  masked
  __shared__ unsigned short Hb[64 * 72];   // [p][n]  h_init
  __shared__ float sdt_all[1024];

  {
    float4 dv = *(const float4*)(dts + tid * 4);
    *(float4*)&sdt_all[tid * 4] = dv;
  }

  f32x4 hacc[4];
#pragma unroll
  for (int j = 0; j < 4; j++) { f32x4 z = {0.f, 0.f, 0.f, 0.f}; hacc[j] = z; }

  for (int c = 0; c < 16; c++) {
    const int t0 = c << 6;
    __syncthreads();                 // prev chunk's LDS readers done (covers sdt on c==0)

    float dtl = sdt_all[t0 + lane];
    float v = dtl;
#pragma unroll
    for (int off = 1; off < 64; off <<= 1) {
      float o = __shfl_up(v, off);
      if (lane >= off) v += o;
    }
    const float Lv = A * v;
    const float ev = expf(Lv);
    const float LL = __shfl(Lv, 63);
    const float wv = dtl * expf(LL - Lv);    // in (0, dt]: safe
    const float dtot = expf(LL);

    // stage h_init -> LDS
#pragma unroll
    for (int j = 0; j < 4; j++)
#pragma unroll
      for (int r = 0; r < 4; r++)
        Hb[(w * 16 + quad * 4 + r) * 72 + j * 16 + lrow] = f2bf(hacc[j][r]);

    // stage Bb/Cb rows (raw, coalesced uint4)
#pragma unroll
    for (int pass = 0; pass < 2; pass++) {
      int u = pass * 256 + tid;
      int sl = u >> 3, c8 = u & 7;
      const unsigned short* rowp = xc + (size_t)(bS + t0 + sl) * CONVDIM;
      uint4 vb = *(const uint4*)(rowp + 1024 + c8 * 8);
      uint4 vc = *(const uint4*)(rowp + 1088 + c8 * 8);
      *(uint4*)&Bb[sl * 72 + c8 * 8] = vb;
      *(uint4*)&Cb[sl * 72 + c8 * 8] = vc;
    }

    // stage Xt (raw) and Bt (* wv_s) via register transpose: 2 channels x 8 timesteps
    {
      unsigned int xv[8], bv[8];
      const unsigned short* base = xc + (size_t)(bS + t0 + sg * 8) * CONVDIM;
#pragma unroll
      for (int k = 0; k < 8; k++) {
        const unsigned short* rp = base + (size_t)k * CONVDIM;
        xv[k] = *(const unsigned int*)(rp + h * 64 + pr * 2);
        bv[k] = *(const unsigned int*)(rp + 1024 + pr * 2);
      }
      unsigned short x0[8], x1[8], b0[8], b1[8];
#pragma unroll
      for (int k = 0; k < 8; k++) {
        float ws = __shfl(wv, sg * 8 + k);
        x0[k] = (unsigned short)(xv[k] & 0xffff);
        x1[k] = (unsigned short)(xv[k] >> 16);
        b0[k] = f2bf(bf2f((unsigned short)(bv[k] & 0xffff)) * ws);
        b1[k] = f2bf(bf2f((unsigned short)(bv[k] >> 16)) * ws);
      }
      *(uint4*)&Xt[(pr * 2 + 0) * 72 + sg * 8] = *(const uint4*)x0;
      *(uint4*)&Xt[(pr * 2 + 1) * 72 + sg * 8] = *(const uint4*)x1;
      *(uint4*)&Bt[(pr * 2 + 0) * 72 + sg * 8] = *(const uint4*)b0;
      *(uint4*)&Bt[(pr * 2 + 1) * 72 + sg * 8] = *(const uint4*)b1;
    }
    __syncthreads();

    // GEMM1: M1[i][s] = C @ B^T (raw)
    f32x4 m1[4];
#pragma unroll
    for (int j = 0; j < 4; j++) { f32x4 z = {0.f, 0.f, 0.f, 0.f}; m1[j] = z; }
#pragma unroll
    for (int kq = 0; kq < 2; kq++) {
      bf16x8 af = *(const bf16x8*)&Cb[(w * 16 + lrow) * 72 + kq * 32 + lk8];
#pragma unroll
      for (int j = 0; j < 4; j++) {
        bf16x8 bf = *(const bf16x8*)&Bb[(j * 16 + lrow) * 72 + kq * 32 + lk8];
        m1[j] = __builtin_amdgcn_mfma_f32_16x16x32_bf16(af, bf, m1[j], 0, 0, 0);
      }
    }
    // mask + decay -> Mb
#pragma unroll
    for (int r = 0; r < 4; r++) {
      int i = w * 16 + quad * 4 + r;
      float Li = __shfl(Lv, i);
#pragma unroll
      for (int j = 0; j < 4; j++) {
        int s = j * 16 + lrow;
        float Ls = __shfl(Lv, s);
        float ds = __shfl(dtl, s);
        float val = (s <= i) ? m1[j][r] * expf(Li - Ls) * ds : 0.f;
        Mb[i * 72 + s] = f2bf(val);
      }
    }
    __syncthreads();

    // Y = M@X ; T = C@H^T ; S = Xt@Bt^T  (Bt already carries wv_s)
    f32x4 Y[4], T[4], S[4];
#pragma unroll
    for (int j = 0; j < 4; j++) {
      f32x4 z = {0.f, 0.f, 0.f, 0.f};
      Y[j] = z; T[j] = z; S[j] = z;
    }
#pragma unroll
    for (int kq = 0; kq < 2; kq++) {
      bf16x8 am = *(const bf16x8*)&Mb[(w * 16 + lrow) * 72 + kq * 32 + lk8];
      bf16x8 ac = *(const bf16x8*)&Cb[(w * 16 + lrow) * 72 + kq * 32 + lk8];
      bf16x8 ax = *(const bf16x8*)&Xt[(w * 16 + lrow) * 72 + kq * 32 + lk8];
#pragma unroll
      for (int j = 0; j < 4; j++) {
        bf16x8 bx = *(const bf16x8*)&Xt[(j * 16 + lrow) * 72 + kq * 32 + lk8];
        bf16x8 bh = *(const bf16x8*)&Hb[(j * 16 + lrow) * 72 + kq * 32 + lk8];
        bf16x8 bw = *(const bf16x8*)&Bt[(j * 16 + lrow) * 72 + kq * 32 + lk8];
        Y[j] = __builtin_amdgcn_mfma_f32_16x16x32_bf16(am, bx, Y[j], 0, 0, 0);
        T[j] = __builtin_amdgcn_mfma_f32_16x16x32_bf16(ac, bh, T[j], 0, 0, 0);
        S[j] = __builtin_amdgcn_mfma_f32_16x16x32_bf16(ax, bw, S[j], 0, 0, 0);
      }
    }

    // combine + store Y (bf16), update h
#pragma unroll
    for (int r = 0; r < 4; r++) {
      int i = w * 16 + quad * 4 + r;
      float ei = __shfl(ev, i);
#pragma unroll
      for (int j = 0; j < 4; j++) {
        int p = j * 16 + lrow;
        float yv = Y[j][r] + ei * T[j][r] + Dh * bf2f(Xt[p * 72 + i]);
        yo[(size_t)(bS + t0 + i) * DINNER + h * 64 + p] = f2bf(yv);
      }
    }
#pragma unroll
    for (int j = 0; j < 4; j++)
#pragma unroll
      for (int r = 0; r < 4; r++)
        hacc[j][r] = dtot * hacc[j][r] + S[j][r];
  }
}

// ---------------- block reduction (256 threads, 4 waves) ----------------
__device__ inline float2 block_sum2_256(float a, float b) {
#pragma unroll
  for (int o = 32; o >= 1; o >>= 1) { a += __shfl_xor(a, o); b += __shfl_xor(b, o); }
  __shared__ float ra[4], rb[4];
  const int lane = threadIdx.x & 63, w = threadIdx.x >> 6;
  if (lane == 0) { ra[w] = a; rb[w] = b; }
  __syncthreads();
  float2 out;
  out.x = ra[0] + ra[1] + ra[2] + ra[3];
  out.y = rb[0] + rb[1] + rb[2] + rb[3];
  return out;
}

// ---------------- combined gate+RMS for BOTH dirs -> comb = gn_f + 0.5*gn_b (bf16) ----
__global__ __launch_bounds__(256)
void gate_rms_comb(const unsigned short* __restrict__ yf, const unsigned short* __restrict__ yb,
                   const unsigned short* __restrict__ zxb, const float* __restrict__ nw,
                   unsigned short* __restrict__ comb) {
  const int bt = blockIdx.x;               // 0..8191 (fwd time == bwd row index)
  const int b = bt >> 10, t = bt & 1023;
  const int zrowb = (b << 10) + (1023 - t);
  const int tid = threadIdx.x;
  ushort4 yf4 = *(const ushort4*)(yf + (size_t)bt * DINNER + tid * 4);
  ushort4 yb4 = *(const ushort4*)(yb + (size_t)bt * DINNER + tid * 4);
  ushort4 zf4 = *(const ushort4*)(zxb + (size_t)bt * DPROJ + tid * 4);
  ushort4 zb4 = *(const ushort4*)(zxb + (size_t)zrowb * DPROJ + tid * 4);
  float gf[4], gb[4];
  {
    float z0 = bf2f(zf4.x), z1 = bf2f(zf4.y), z2 = bf2f(zf4.z), z3 = bf2f(zf4.w);
    gf[0] = bf2f(yf4.x) * (z0 / (1.f + expf(-z0)));
    gf[1] = bf2f(yf4.y) * (z1 / (1.f + expf(-z1)));
    gf[2] = bf2f(yf4.z) * (z2 / (1.f + expf(-z2)));
    gf[3] = bf2f(yf4.w) * (z3 / (1.f + expf(-z3)));
  }
  {
    float z0 = bf2f(zb4.x), z1 = bf2f(zb4.y), z2 = bf2f(zb4.z), z3 = bf2f(zb4.w);
    gb[0] = bf2f(yb4.x) * (z0 / (1.f + expf(-z0)));
    gb[1] = bf2f(yb4.y) * (z1 / (1.f + expf(-z1)));
    gb[2] = bf2f(yb4.z) * (z2 / (1.f + expf(-z2)));
    gb[3] = bf2f(yb4.w) * (z3 / (1.f + expf(-z3)));
  }
  float2 sr = block_sum2_256(gf[0]*gf[0] + gf[1]*gf[1] + gf[2]*gf[2] + gf[3]*gf[3],
                             gb[0]*gb[0] + gb[1]*gb[1] + gb[2]*gb[2] + gb[3]*gb[3]);
  float sf = rsqrtf(sr.x * (1.f / 1024.f) + 1e-5f);
  float sb = 0.5f * rsqrtf(sr.y * (1.f / 1024.f) + 1e-5f);
  float4 wv = *(const float4*)(nw + tid * 4);
  unsigned short* o = comb + (size_t)bt * DINNER + tid * 4;
  o[0] = f2bf((gf[0] * sf + gb[0] * sb) * wv.x);
  o[1] = f2bf((gf[1] * sf + gb[1] * sb) * wv.y);
  o[2] = f2bf((gf[2] * sf + gb[2] * sb) * wv.z);
  o[3] = f2bf((gf[3] * sf + gb[3] * sb) * wv.w);
}

// ---------------- h = sum of 4 bf16 partials + u; layernorm -> fp32 + bf16 ----------------
__global__ __launch_bounds__(256)
void combine_ln(const unsigned short* __restrict__ mo, const float* __restrict__ u,
                const float* __restrict__ w, const float* __restrict__ bias,
                float* __restrict__ hln, unsigned short* __restrict__ hbf) {
  const int bt = blockIdx.x;
  const int tid = threadIdx.x;
  const float2 uu = *(const float2*)(u + (size_t)bt * DMODEL + tid * 2);
  float vx = uu.x, vy = uu.y;
#pragma unroll
  for (int z = 0; z < 4; z++) {
    ushort2 p = *(const ushort2*)(mo + (size_t)z * NTOK * DMODEL + (size_t)bt * DMODEL + tid * 2);
    vx += bf2f(p.x);
    vy += bf2f(p.y);
  }
  float2 sr = block_sum2_256(vx + vy, vx * vx + vy * vy);
  float mean = sr.x * (1.f / 512.f);
  float var = sr.y * (1.f / 512.f) - mean * mean;
  float inv = rsqrtf(var + 1e-12f);
  float2 wv = *(const float2*)(w + tid * 2);
  float2 bv = *(const float2*)(bias + tid * 2);
  float ox = (vx - mean) * inv * wv.x + bv.x;
  float oy = (vy - mean) * inv * wv.y + bv.y;
  *(float2*)(hln + (size_t)bt * DMODEL + tid * 2) = make_float2(ox, oy);
  hbf[(size_t)bt * DMODEL + tid * 2] = f2bf(ox);
  hbf[(size_t)bt * DMODEL + tid * 2 + 1] = f2bf(oy);
}

// ---------------- out = layernorm(sum of 4 bf16 partials + b2 + hln) ----------------
__global__ __launch_bounds__(256)
void final_ln(const unsigned short* __restrict__ f2, const float* __restrict__ b2,
              const float* __restrict__ hln,
              const float* __restrict__ w, const float* __restrict__ bias,
              float* __restrict__ outp) {
  const int bt = blockIdx.x;
  const int tid = threadIdx.x;
  const float2 bb = *(const float2*)(b2 + tid * 2);
  const float2 h = *(const float2*)(hln + (size_t)bt * DMODEL + tid * 2);
  float vx = bb.x + h.x;
  float vy = bb.y + h.y;
#pragma unroll
  for (int z = 0; z < 4; z++) {
    ushort2 p = *(const ushort2*)(f2 + (size_t)z * NTOK * DMODEL + (size_t)bt * DMODEL + tid * 2);
    vx += bf2f(p.x);
    vy += bf2f(p.y);
  }
  float2 sr = block_sum2_256(vx + vy, vx * vx + vy * vy);
  float mean = sr.x * (1.f / 512.f);
  float var = sr.y * (1.f / 512.f) - mean * mean;
  float inv = rsqrtf(var + 1e-12f);
  float2 wv = *(const float2*)(w + tid * 2);
  float2 bv = *(const float2*)(bias + tid * 2);
  *(float2*)(outp + (size_t)bt * DMODEL + tid * 2) =
      make_float2((vx - mean) * inv * wv.x + bv.x, (vy - mean) * inv * wv.y + bv.y);
}

extern "C" void kernel_launch(void* const* d_in, const int* in_sizes, int n_in,
                              void* d_out, int out_size, void* d_ws, size_t ws_size,
                              hipStream_t stream) {
  const float* item_emb   = (const float*)d_in[0];
  const float* in_proj_w  = (const float*)d_in[3];
  const float* conv_w     = (const float*)d_in[4];
  const float* conv_b     = (const float*)d_in[5];
  const float* dt_bias    = (const float*)d_in[6];
  const float* A_log      = (const float*)d_in[7];
  const float* Dp         = (const float*)d_in[8];
  const float* norm_w     = (const float*)d_in[9];
  const float* out_proj_w = (const float*)d_in[10];
  const float* ln_w       = (const float*)d_in[11];
  const float* ln_b       = (const float*)d_in[12];
  const float* w1         = (const float*)d_in[13];
  const float* b1         = (const float*)d_in[14];
  const float* w2         = (const float*)d_in[15];
  const float* b2         = (const float*)d_in[16];
  const float* fln_w      = (const float*)d_in[17];
  const float* fln_b      = (const float*)d_in[18];
  float* outp = (float*)d_out;
  char* ws = (char*)d_ws;

  // ---- workspace layout (bytes) ----
  const size_t o_ubf  = 0;                 // [8192,512]  bf16    8,388,608
  const size_t o_win  = 8388608;           // [2304,512]  bf16    2,359,296
  const size_t o_wout = 10747904;          // [512,1024]  bf16    1,048,576
  const size_t o_w1   = 11796480;          // [2048,512]  bf16    2,097,152
  const size_t o_w2   = 13893632;          // [512,2048]  bf16    2,097,152
  const size_t o_dtf  = 15990784;          // [128,1024]  f32       524,288
  const size_t o_dtb  = 16515072;
  const size_t o_zdt  = 17039360;          // [8192,16]   f32       524,288
  const size_t o_zxb  = 17563648;          // [8192,2192] bf16   35,913,728
  const size_t o_xcf  = 53477376;          // [8192,1152] bf16   18,874,368
  const size_t o_xcb  = 72351744;          // [8192,1152] bf16   18,874,368
  const size_t o_yf   = 91226112;          // [8192,1024] bf16   16,777,216
  const size_t o_yb   = 108003328;         //               end 124,780,544
  // phase-2 aliases (regions dead by the time these are written)
  const size_t o_comb = o_xcf;             // [8192,1024]   bf16 (xcf dead after ssd)
  const size_t o_mo   = o_zxb;             // 4x[8192,512]  bf16 33.5MB (zxb dead after gate_rms_comb)
  const size_t o_hln  = o_yb;              // [8192,512]    f32  (yb dead after gate_rms_comb)
  const size_t o_hbf  = o_ubf;             // [8192,512]    bf16 (u_bf dead after in-proj)
  const size_t o_h1   = o_xcb;             // [8192,2048]   bf16 33.6MB (xcb+yf dead)
  const size_t o_f2   = o_zxb;             // 4x[8192,512]  bf16 (mo dead after combine_ln)

  unsigned short* u_bf  = (unsigned short*)(ws + o_ubf);
  unsigned short* winb  = (unsigned short*)(ws + o_win);
  unsigned short* woutb = (unsigned short*)(ws + o_wout);
  unsigned short* w1b   = (unsigned short*)(ws + o_w1);
  unsigned short* w2b   = (unsigned short*)(ws + o_w2);
  float* dtf = (float*)(ws + o_dtf);
  float* dtb = (float*)(ws + o_dtb);
  float* zdt = (float*)(ws + o_zdt);
  unsigned short* zxb = (unsigned short*)(ws + o_zxb);
  unsigned short* xcf = (unsigned short*)(ws + o_xcf);
  unsigned short* xcb = (unsigned short*)(ws + o_xcb);
  unsigned short* yf  = (unsigned short*)(ws + o_yf);
  unsigned short* yb  = (unsigned short*)(ws + o_yb);
  unsigned short* comb = (unsigned short*)(ws + o_comb);
  unsigned short* mo  = (unsigned short*)(ws + o_mo);
  float* hln = (float*)(ws + o_hln);
  unsigned short* hbf = (unsigned short*)(ws + o_hbf);
  unsigned short* h1b = (unsigned short*)(ws + o_h1);
  unsigned short* f2  = (unsigned short*)(ws + o_f2);

  // ---- bf16 conversions ----
  {
    int n = NTOK * DMODEL;
    cvt_bf16<<<(n + 255) / 256, 256, 0, stream>>>(item_emb, u_bf, n);
    cvt_bf16_pad<<<(DPROJP * DMODEL + 255) / 256, 256, 0, stream>>>(in_proj_w, winb, DPROJ, DMODEL, DPROJP);
    n = DMODEL * DINNER;
    cvt_bf16<<<(n + 255) / 256, 256, 0, stream>>>(out_proj_w, woutb, n);
    n = DFFN * DMODEL;
    cvt_bf16<<<(n + 255) / 256, 256, 0, stream>>>(w1, w1b, n);
    n = DMODEL * DFFN;
    cvt_bf16<<<(n + 255) / 256, 256, 0, stream>>>(w2, w2b, n);
  }

  // ---- in-proj: zxb[8192,2192](bf16) = u @ in_proj_w^T ; dt cols fp32 -> zdt ----
  gemm_bt<2><<<dim3(DPROJP / 128, NTOK / 128), 256, 0, stream>>>(
      u_bf, winb, zxb, nullptr, zdt, DMODEL, DMODEL, DPROJ, 0);

  // ---- dt (softplus) to [dir][(b*16+h)][t]; conv+silu both dirs ----
  dt_softplus<<<1024, 256, 0, stream>>>(zdt, dt_bias, dtf, dtb);
  conv_silu_bf<<<dim3(9, NBATCH, 16), 256, 0, stream>>>(zxb, conv_w, conv_b, xcf, xcb);

  // ---- chunked SSD: 256 blocks = (dir,b,h) ----
  ssd_chunk<<<256, 256, 0, stream>>>(xcf, xcb, dtf, dtb, A_log, Dp, yf, yb);

  // ---- fused gate + RMS + dir-combine -> comb[8192,1024] bf16 ----
  gate_rms_comb<<<NTOK, 256, 0, stream>>>(yf, yb, zxb, norm_w, comb);

  // ---- out-proj: mo = comb @ out_proj_w^T, split-K=4 (bf16 partials) ----
  gemm_bt<3><<<dim3(DMODEL / 128, NTOK / 128, 4), 256, 0, stream>>>(
      comb, woutb, mo, nullptr, nullptr, DINNER / 4, DINNER, DMODEL,
      (size_t)NTOK * DMODEL);

  // ---- combine + first layernorm (sums 4 partials) ----
  combine_ln<<<NTOK, 256, 0, stream>>>(mo, item_emb, ln_w, ln_b, hln, hbf);

  // ---- FFN1: h1 = gelu(hln @ w1^T + b1) -> bf16 ----
  gemm_bt<1><<<dim3(DFFN / 128, NTOK / 128), 256, 0, stream>>>(
      hbf, w1b, h1b, b1, nullptr, DMODEL, DMODEL, DFFN, 0);

  // ---- FFN2: f2 = h1 @ w2^T, split-K=4 (bf16 partials; bias b2 in final_ln) ----
  gemm_bt<3><<<dim3(DMODEL / 128, NTOK / 128, 4), 256, 0, stream>>>(
      h1b, w2b, f2, nullptr, nullptr, DFFN / 4, DFFN, DMODEL,
      (size_t)NTOK * DMODEL);

  // ---- final layernorm (sums 4 partials + b2) -> d_out ----
  final_ln<<<NTOK, 256, 0, stream>>>(f2, b2, hln, fln_w, fln_b, outp);

  (void)in_sizes; (void)n_in; (void)out_size; (void)ws_size;
}